// Round 1
// baseline (296.043 us; speedup 1.0000x reference)
//
#include <hip/hip_runtime.h>
#include <stdint.h>

typedef __attribute__((ext_vector_type(8))) short short8;
typedef __attribute__((ext_vector_type(4))) float f32x4;

#define DEVI __device__ __forceinline__

DEVI unsigned short f2bf(float f) {
  union { float f; uint32_t u; } v; v.f = f;
  return (unsigned short)((v.u + 0x7fffu + ((v.u >> 16) & 1u)) >> 16);
}

DEVI void gload_lds16(const void* g, void* l) {
  __builtin_amdgcn_global_load_lds(
      (const __attribute__((address_space(1))) uint32_t*)g,
      (__attribute__((address_space(3))) uint32_t*)l, 16, 0, 0);
}

// ---------------- K0: positional encoding table T[256][32] ----------------
__global__ void k_petab(float* __restrict__ T) {
  int c = threadIdx.x;  // 256 threads
  int idx = ((c >= 128) ? c - 128 : c) >> 1;
  float freq = expf(-(float)idx * (logf(10000.0f) / 64.0f));
  for (int p = 0; p < 32; ++p) {
    float ang = (float)p * freq;
    T[c * 32 + p] = (c & 1) ? cosf(ang) : sinf(ang);
  }
}

// ---------------- K1: xpT = (x + pe) transposed to [b*1024+n][256], f32 + bf16 ----------------
__global__ __launch_bounds__(256) void k_xpt(const float* __restrict__ x,
                                             const float* __restrict__ T,
                                             unsigned short* __restrict__ xpt_bf,
                                             float* __restrict__ xpt_f) {
  __shared__ __align__(16) float tile[32][36];  // [n][c]
  const int b = blockIdx.z, c0 = blockIdx.x * 32, n0 = blockIdx.y * 32;
  const int t = threadIdx.x;
  {
    const int cl = t >> 3, ng = (t & 7) * 4;
    const int c = c0 + cl;
    float4 v = *(const float4*)(x + ((size_t)b * 256 + c) * 1024 + n0 + ng);
    float p0, p1, p2, p3;
    if (c < 128) {  // depends on w = n&31
      p0 = T[c * 32 + ng + 0]; p1 = T[c * 32 + ng + 1];
      p2 = T[c * 32 + ng + 2]; p3 = T[c * 32 + ng + 3];
    } else {        // depends on h = n>>5 (uniform over the 32-wide n-tile)
      p0 = p1 = p2 = p3 = T[c * 32 + (n0 >> 5)];
    }
    tile[ng + 0][cl] = v.x + p0;
    tile[ng + 1][cl] = v.y + p1;
    tile[ng + 2][cl] = v.z + p2;
    tile[ng + 3][cl] = v.w + p3;
  }
  __syncthreads();
  {
    const int nl = t >> 3, cg = (t & 7) * 4;
    float o0 = tile[nl][cg + 0], o1 = tile[nl][cg + 1];
    float o2 = tile[nl][cg + 2], o3 = tile[nl][cg + 3];
    size_t row = (size_t)b * 1024 + n0 + nl;
    *(float4*)(xpt_f + row * 256 + c0 + cg) = make_float4(o0, o1, o2, o3);
    uint32_t lo = (uint32_t)f2bf(o0) | ((uint32_t)f2bf(o1) << 16);
    uint32_t hi = (uint32_t)f2bf(o2) | ((uint32_t)f2bf(o3) << 16);
    *(uint2*)(xpt_bf + row * 256 + c0 + cg) = make_uint2(lo, hi);
  }
}

// ---------------- K2: pack conv weights -> Wpack[1536][2304] bf16, k = (kh*3+kw)*256 + ci ----------------
__global__ void k_packw(const float* __restrict__ Wk, const float* __restrict__ Wq,
                        const float* __restrict__ Wv, unsigned short* __restrict__ Wpack) {
  int i = blockIdx.x * 256 + threadIdx.x;
  if (i >= 1536 * 2304) return;
  int o = i / 2304, kn = i % 2304;
  int ci = kn & 255, khw = kn >> 8;  // 2304 = 9*256
  const float* src = (o < 512) ? Wk : ((o < 1024) ? Wq : Wv);
  int oo = o & 511;
  Wpack[i] = f2bf(src[((size_t)oo * 256 + ci) * 9 + khw]);
}

// ---------------- K3: misc packs (bias concat, permuted Wproj, W1/W2 casts) ----------------
__global__ void k_packmisc(const float* __restrict__ bk, const float* __restrict__ bq,
                           const float* __restrict__ bv, const float* __restrict__ Wproj,
                           const float* __restrict__ W1, const float* __restrict__ W2,
                           float* __restrict__ bias_kqv, unsigned short* __restrict__ WprojP,
                           unsigned short* __restrict__ W1b, unsigned short* __restrict__ W2b) {
  int i = blockIdx.x * 256 + threadIdx.x;  // 512*256 = 131072 threads
  if (i < 1536)
    bias_kqv[i] = (i < 512) ? bk[i] : ((i < 1024) ? bq[i - 512] : bv[i - 1024]);
  if (i < 131072) {
    int j = i >> 9, f = i & 511;
    int h = f >> 6, c = f & 63;
    WprojP[i] = f2bf(Wproj[(size_t)j * 512 + c * 8 + h]);  // fold att reshape (c*8+h) into weight
  }
  if (i < 65536) {
    W1b[i] = f2bf(W1[i]);
    W2b[i] = f2bf(W2[i]);
  }
}

// ---------------- K4: im2col -> xcolT[b*1024+n][2304] bf16 ----------------
__global__ __launch_bounds__(256) void k_im2col(const unsigned short* __restrict__ xpt_bf,
                                                unsigned short* __restrict__ xcol) {
  const int b = blockIdx.y;
  int t = blockIdx.x * 256 + threadIdx.x;  // < 1024*9*32
  int ci8 = t & 31;
  int rest = t >> 5;
  int khw = rest % 9;
  int n = rest / 9;
  int y = n >> 5, xq = n & 31;
  int ky = y + khw / 3 - 1, kx = xq + khw % 3 - 1;
  uint4 val = make_uint4(0u, 0u, 0u, 0u);
  if (ky >= 0 && ky < 32 && kx >= 0 && kx < 32)
    val = *(const uint4*)&xpt_bf[((size_t)b * 1024 + ky * 32 + kx) * 256 + ci8 * 8];
  *(uint4*)&xcol[((size_t)b * 1024 + n) * 2304 + khw * 256 + ci8 * 8] = val;
}

// ---------------- GEMM: C[M][N] = A[M][K] * B[N][K]^T  (both K-major bf16, f32 acc) ----------------
// EPI 0: bf16 out, + bias[col]                (conv K,Q -> kq_t)
// EPI 1: bf16 out, + bias[row]                (conv V -> v)
// EPI 2: f32 out,  + bias[col] + resid[row*N+col]   (attproj / FFN2)
// EPI 3: bf16 out, + bias[col], LeakyReLU(0.1)      (FFN1)
template <int EPI>
__global__ __launch_bounds__(256) void k_gemm(const unsigned short* __restrict__ A,
                                              const unsigned short* __restrict__ B,
                                              void* __restrict__ Cout,
                                              const float* __restrict__ bias,
                                              const float* __restrict__ resid,
                                              int M, int N, int K,
                                              size_t aBatch, size_t bBatch, size_t cBatch) {
  __shared__ __align__(16) unsigned short As[128 * 64];
  __shared__ __align__(16) unsigned short Bs[128 * 64];
  const int tid = threadIdx.x, l = tid & 63, w = tid >> 6;
  const int wm = w >> 1, wn = w & 1;
  const int m0 = blockIdx.x * 128, n0 = blockIdx.y * 128;
  const int bz = blockIdx.z;
  const char* Ab = (const char*)(A + (size_t)bz * aBatch);
  const char* Bb = (const char*)(B + (size_t)bz * bBatch);

  f32x4 acc[4][4] = {};

  for (int kt = 0; kt < K; kt += 64) {
#pragma unroll
    for (int j = 0; j < 4; ++j) {
      int seg = w * 4 + j;
      int r8 = seg * 8 + (l >> 3);
      int cb = (l & 7) * 16;
      gload_lds16(Ab + ((size_t)(m0 + r8) * K + kt) * 2 + cb, (char*)As + seg * 1024);
      gload_lds16(Bb + ((size_t)(n0 + r8) * K + kt) * 2 + cb, (char*)Bs + seg * 1024);
    }
    __syncthreads();
#pragma unroll
    for (int kk = 0; kk < 2; ++kk) {
      short8 af[4], bfr[4];
#pragma unroll
      for (int fm = 0; fm < 4; ++fm)
        af[fm] = *(const short8*)((const char*)As +
                                  (wm * 64 + fm * 16 + (l & 15)) * 128 + kk * 64 + (l >> 4) * 16);
#pragma unroll
      for (int fn = 0; fn < 4; ++fn)
        bfr[fn] = *(const short8*)((const char*)Bs +
                                   (wn * 64 + fn * 16 + (l & 15)) * 128 + kk * 64 + (l >> 4) * 16);
#pragma unroll
      for (int fm = 0; fm < 4; ++fm)
#pragma unroll
        for (int fn = 0; fn < 4; ++fn)
          acc[fm][fn] = __builtin_amdgcn_mfma_f32_16x16x32_bf16(af[fm], bfr[fn], acc[fm][fn], 0, 0, 0);
    }
    __syncthreads();
  }

#pragma unroll
  for (int fm = 0; fm < 4; ++fm)
#pragma unroll
    for (int fn = 0; fn < 4; ++fn)
#pragma unroll
      for (int r = 0; r < 4; ++r) {
        int row = m0 + wm * 64 + fm * 16 + (l >> 4) * 4 + r;
        int col = n0 + wn * 64 + fn * 16 + (l & 15);
        float v = acc[fm][fn][r];
        size_t cidx = (size_t)bz * cBatch + (size_t)row * N + col;
        if (EPI == 0) {
          v += bias[col];
          ((unsigned short*)Cout)[cidx] = f2bf(v);
        } else if (EPI == 1) {
          v += bias[row];
          ((unsigned short*)Cout)[cidx] = f2bf(v);
        } else if (EPI == 2) {
          v += bias[col] + resid[(size_t)row * N + col];
          ((float*)Cout)[cidx] = v;
        } else {
          v += bias[col];
          v = (v > 0.f) ? v : 0.1f * v;
          ((unsigned short*)Cout)[cidx] = f2bf(v);
        }
      }
}

// ---------------- K5: fused attention (head-softmax), 8 waves = 8 heads, n-tile=32 ----------------
__global__ __launch_bounds__(512) void k_attn(const unsigned short* __restrict__ kq_t,
                                              const unsigned short* __restrict__ v,
                                              unsigned short* __restrict__ att_t) {
  __shared__ __align__(16) unsigned short Qs[32 * 512];   // [m'][h*64+c]
  __shared__ __align__(16) unsigned short Vs[512 * 32];   // [h*64+c][m']
  __shared__ __align__(16) float Ss[8 * 32 * 32];         // [h][n'][m']
  __shared__ __align__(16) unsigned short Ps[8 * 32 * 32];// [h][n'][m']
  const int tid = threadIdx.x, l = tid & 63, h = tid >> 6;
  const int n0 = blockIdx.x * 32, bb = blockIdx.y;
  const size_t kqBase = (size_t)bb * 1024 * 1024;

  // K fragments (A operand), held in registers for the whole kernel.
  short8 ak[2][2];
#pragma unroll
  for (int fn = 0; fn < 2; ++fn)
#pragma unroll
    for (int fc = 0; fc < 2; ++fc)
      ak[fn][fc] = *(const short8*)&kq_t[kqBase + (size_t)(n0 + fn * 16 + (l & 15)) * 1024 +
                                         h * 64 + fc * 32 + (l >> 4) * 8];

  f32x4 oacc[2][4] = {};

  for (int m0 = 0; m0 < 1024; m0 += 32) {
#pragma unroll
    for (int j = 0; j < 4; ++j) {
      int seg = h * 4 + j;
      // Q tile: row m'=seg (1024B rows), q features are cols 512..1024 of kq_t
      gload_lds16((const char*)kq_t + (kqBase + (size_t)(m0 + seg) * 1024 + 512) * 2 + l * 16,
                  (char*)Qs + seg * 1024);
      // V tile: 64B rows [hc][m'], seg covers 16 rows
      int hc = seg * 16 + (l >> 2);
      gload_lds16((const char*)v + (((size_t)bb * 512 + hc) * 1024 + m0 + (l & 3) * 8) * 2,
                  (char*)Vs + seg * 1024);
    }
    __syncthreads();

    // --- QK^T for this head: S[n'][m'] ---
    f32x4 s[2][2] = {};
#pragma unroll
    for (int kk = 0; kk < 2; ++kk) {
      short8 bq[2];
#pragma unroll
      for (int fm = 0; fm < 2; ++fm)
        bq[fm] = *(const short8*)((const char*)Qs + (fm * 16 + (l & 15)) * 1024 +
                                  (h * 64 + kk * 32 + (l >> 4) * 8) * 2);
#pragma unroll
      for (int fn = 0; fn < 2; ++fn)
#pragma unroll
        for (int fm = 0; fm < 2; ++fm)
          s[fn][fm] = __builtin_amdgcn_mfma_f32_16x16x32_bf16(ak[fn][kk], bq[fm], s[fn][fm], 0, 0, 0);
    }
#pragma unroll
    for (int fn = 0; fn < 2; ++fn)
#pragma unroll
      for (int fm = 0; fm < 2; ++fm)
#pragma unroll
        for (int r = 0; r < 4; ++r) {
          int np = fn * 16 + (l >> 4) * 4 + r, mp = fm * 16 + (l & 15);
          Ss[h * 1024 + np * 32 + mp] = s[fn][fm][r] * (1.0f / 1024.0f);
        }
    __syncthreads();

    // --- softmax over the 8 heads (cross-wave through LDS) ---
#pragma unroll
    for (int pp = 0; pp < 2; ++pp) {
      int p = tid + pp * 512;
      float e[8];
      float mx = -1e30f;
#pragma unroll
      for (int hh = 0; hh < 8; ++hh) { e[hh] = Ss[hh * 1024 + p]; mx = fmaxf(mx, e[hh]); }
      float sum = 0.f;
#pragma unroll
      for (int hh = 0; hh < 8; ++hh) { e[hh] = __expf(e[hh] - mx); sum += e[hh]; }
      float inv = 1.0f / sum;
#pragma unroll
      for (int hh = 0; hh < 8; ++hh) Ps[hh * 1024 + p] = f2bf(e[hh] * inv);
    }
    __syncthreads();

    // --- P @ V^T accumulate: oacc[n'][c] ---
    short8 ap[2];
#pragma unroll
    for (int fn = 0; fn < 2; ++fn)
      ap[fn] = *(const short8*)((const char*)Ps +
                                (h * 1024 + (fn * 16 + (l & 15)) * 32 + (l >> 4) * 8) * 2);
#pragma unroll
    for (int fc = 0; fc < 4; ++fc) {
      short8 bv8 = *(const short8*)((const char*)Vs +
                                    ((h * 64 + fc * 16 + (l & 15)) * 32 + (l >> 4) * 8) * 2);
#pragma unroll
      for (int fn = 0; fn < 2; ++fn)
        oacc[fn][fc] = __builtin_amdgcn_mfma_f32_16x16x32_bf16(ap[fn], bv8, oacc[fn][fc], 0, 0, 0);
    }
    __syncthreads();
  }

#pragma unroll
  for (int fn = 0; fn < 2; ++fn)
#pragma unroll
    for (int fc = 0; fc < 4; ++fc)
#pragma unroll
      for (int r = 0; r < 4; ++r) {
        int np = fn * 16 + (l >> 4) * 4 + r, c = fc * 16 + (l & 15);
        att_t[((size_t)bb * 1024 + n0 + np) * 512 + h * 64 + c] = f2bf(oacc[fn][fc][r]);
      }
}

// ---------------- K6: LayerNorm over rows of [8192][256] ----------------
// MODE 0: write f32 + bf16; MODE 1: write f32 only
template <int MODE>
__global__ __launch_bounds__(256) void k_ln(const float* __restrict__ in,
                                            const float* __restrict__ g,
                                            const float* __restrict__ bta,
                                            float* __restrict__ out_f,
                                            unsigned short* __restrict__ out_b) {
  const int l = threadIdx.x & 63, w = threadIdx.x >> 6;
  const size_t row = (size_t)blockIdx.x * 4 + w;
  float4 xv = *(const float4*)(in + row * 256 + l * 4);
  float s = xv.x + xv.y + xv.z + xv.w;
  float q = xv.x * xv.x + xv.y * xv.y + xv.z * xv.z + xv.w * xv.w;
#pragma unroll
  for (int o = 1; o < 64; o <<= 1) {
    s += __shfl_xor(s, o, 64);
    q += __shfl_xor(q, o, 64);
  }
  float mu = s * (1.0f / 256.0f);
  float var = q * (1.0f / 256.0f) - mu * mu;
  float rstd = rsqrtf(var + 1e-5f);
  float4 gv = *(const float4*)(g + l * 4);
  float4 bv = *(const float4*)(bta + l * 4);
  float o0 = (xv.x - mu) * rstd * gv.x + bv.x;
  float o1 = (xv.y - mu) * rstd * gv.y + bv.y;
  float o2 = (xv.z - mu) * rstd * gv.z + bv.z;
  float o3 = (xv.w - mu) * rstd * gv.w + bv.w;
  *(float4*)(out_f + row * 256 + l * 4) = make_float4(o0, o1, o2, o3);
  if (MODE == 0) {
    uint32_t lo = (uint32_t)f2bf(o0) | ((uint32_t)f2bf(o1) << 16);
    uint32_t hi = (uint32_t)f2bf(o2) | ((uint32_t)f2bf(o3) << 16);
    *(uint2*)(out_b + row * 256 + l * 4) = make_uint2(lo, hi);
  }
}

// ---------------- K7: transpose [b*1024+n][256] -> d_out [b][256][1024] ----------------
__global__ __launch_bounds__(256) void k_transout(const float* __restrict__ in,
                                                  float* __restrict__ out) {
  __shared__ __align__(16) float tile[32][36];  // [c][n]
  const int b = blockIdx.z, c0 = blockIdx.x * 32, n0 = blockIdx.y * 32;
  const int t = threadIdx.x;
  {
    const int nl = t >> 3, cg = (t & 7) * 4;
    float4 v = *(const float4*)(in + ((size_t)b * 1024 + n0 + nl) * 256 + c0 + cg);
    tile[cg + 0][nl] = v.x;
    tile[cg + 1][nl] = v.y;
    tile[cg + 2][nl] = v.z;
    tile[cg + 3][nl] = v.w;
  }
  __syncthreads();
  {
    const int cl = t >> 3, ng = (t & 7) * 4;
    float4 o = make_float4(tile[cl][ng + 0], tile[cl][ng + 1], tile[cl][ng + 2], tile[cl][ng + 3]);
    *(float4*)(out + ((size_t)b * 256 + c0 + cl) * 1024 + n0 + ng) = o;
  }
}

// ---------------- host launcher ----------------
extern "C" void kernel_launch(void* const* d_in, const int* in_sizes, int n_in,
                              void* d_out, int out_size, void* d_ws, size_t ws_size,
                              hipStream_t stream) {
  const float* x     = (const float*)d_in[0];
  const float* Wk    = (const float*)d_in[1];
  const float* bk    = (const float*)d_in[2];
  const float* Wq    = (const float*)d_in[3];
  const float* bq    = (const float*)d_in[4];
  const float* Wv    = (const float*)d_in[5];
  const float* bv    = (const float*)d_in[6];
  const float* Wproj = (const float*)d_in[7];
  const float* bproj = (const float*)d_in[8];
  const float* ln_g  = (const float*)d_in[9];
  const float* ln_b  = (const float*)d_in[10];
  const float* W1    = (const float*)d_in[11];
  const float* b1    = (const float*)d_in[12];
  const float* W2    = (const float*)d_in[13];
  const float* b2    = (const float*)d_in[14];

  char* ws = (char*)d_ws;
  constexpr size_t OFF_XPTB  = 0;                                    // bf16 [8192][256]
  constexpr size_t OFF_XPTF  = OFF_XPTB  + (size_t)8192 * 256 * 2;   // f32  [8192][256]
  constexpr size_t OFF_WPACK = OFF_XPTF  + (size_t)8192 * 256 * 4;   // bf16 [1536][2304]
  constexpr size_t OFF_BIAS  = OFF_WPACK + (size_t)1536 * 2304 * 2;  // f32  [1536]
  constexpr size_t OFF_WPROJ = OFF_BIAS  + (size_t)1536 * 4;         // bf16 [256][512]
  constexpr size_t OFF_W1B   = OFF_WPROJ + (size_t)256 * 512 * 2;    // bf16 [256][256]
  constexpr size_t OFF_W2B   = OFF_W1B   + (size_t)256 * 256 * 2;    // bf16 [256][256]
  constexpr size_t OFF_PET   = OFF_W2B   + (size_t)256 * 256 * 2;    // f32  [256][32]
  constexpr size_t OFF_KQT   = OFF_PET   + (size_t)256 * 32 * 4;     // bf16 [8192][1024]
  constexpr size_t OFF_V     = OFF_KQT   + (size_t)8192 * 1024 * 2;  // bf16 [8][512][1024]
  constexpr size_t OFF_ATT   = OFF_V     + (size_t)8 * 512 * 1024 * 2; // bf16 [8192][512]
  constexpr size_t OFF_X     = OFF_ATT   + (size_t)8192 * 512 * 2;
  // region X: im2col during convs, then reused by the FFN-phase buffers
  constexpr size_t OFF_XCOL  = OFF_X;                                // bf16 [8192][2304]
  constexpr size_t OFF_Y1    = OFF_X;                                // f32 [8192][256]
  constexpr size_t OFF_ADDNF = OFF_Y1    + (size_t)8192 * 256 * 4;   // f32
  constexpr size_t OFF_ADDNB = OFF_ADDNF + (size_t)8192 * 256 * 4;   // bf16
  constexpr size_t OFF_H1    = OFF_ADDNB + (size_t)8192 * 256 * 2;   // bf16
  constexpr size_t OFF_H2    = OFF_H1    + (size_t)8192 * 256 * 2;   // f32

  (void)in_sizes; (void)n_in; (void)out_size; (void)ws_size;

  k_petab<<<1, 256, 0, stream>>>((float*)(ws + OFF_PET));
  k_xpt<<<dim3(8, 32, 8), 256, 0, stream>>>(x, (const float*)(ws + OFF_PET),
                                            (unsigned short*)(ws + OFF_XPTB),
                                            (float*)(ws + OFF_XPTF));
  k_packw<<<(1536 * 2304 + 255) / 256, 256, 0, stream>>>(Wk, Wq, Wv,
                                                         (unsigned short*)(ws + OFF_WPACK));
  k_packmisc<<<512, 256, 0, stream>>>(bk, bq, bv, Wproj, W1, W2,
                                      (float*)(ws + OFF_BIAS),
                                      (unsigned short*)(ws + OFF_WPROJ),
                                      (unsigned short*)(ws + OFF_W1B),
                                      (unsigned short*)(ws + OFF_W2B));
  k_im2col<<<dim3(1152, 8), 256, 0, stream>>>((const unsigned short*)(ws + OFF_XPTB),
                                              (unsigned short*)(ws + OFF_XCOL));
  // conv K+Q: C[n][o] = xcol[n][k] . Wkq[o][k]   (M=8192, N=1024, K=2304)
  k_gemm<0><<<dim3(64, 8, 1), 256, 0, stream>>>((const unsigned short*)(ws + OFF_XCOL),
                                                (const unsigned short*)(ws + OFF_WPACK),
                                                ws + OFF_KQT, (const float*)(ws + OFF_BIAS),
                                                nullptr, 8192, 1024, 2304, 0, 0, 0);
  // conv V: C[o][m] = Wv[o][k] . xcol[m][k]      (M=512, N=1024, K=2304, batched over b)
  k_gemm<1><<<dim3(4, 8, 8), 256, 0, stream>>>((const unsigned short*)(ws + OFF_WPACK) + (size_t)1024 * 2304,
                                               (const unsigned short*)(ws + OFF_XCOL),
                                               ws + OFF_V, (const float*)(ws + OFF_BIAS) + 1024,
                                               nullptr, 512, 1024, 2304,
                                               0, (size_t)1024 * 2304, (size_t)512 * 1024);
  k_attn<<<dim3(32, 8), 512, 0, stream>>>((const unsigned short*)(ws + OFF_KQT),
                                          (const unsigned short*)(ws + OFF_V),
                                          (unsigned short*)(ws + OFF_ATT));
  // attproj + bias + residual(x+pe): y1 f32      (M=8192, N=256, K=512)
  k_gemm<2><<<dim3(64, 2, 1), 256, 0, stream>>>((const unsigned short*)(ws + OFF_ATT),
                                                (const unsigned short*)(ws + OFF_WPROJ),
                                                ws + OFF_Y1, bproj,
                                                (const float*)(ws + OFF_XPTF),
                                                8192, 256, 512, 0, 0, 0);
  k_ln<0><<<2048, 256, 0, stream>>>((const float*)(ws + OFF_Y1), ln_g, ln_b,
                                    (float*)(ws + OFF_ADDNF), (unsigned short*)(ws + OFF_ADDNB));
  // FFN1 + LeakyReLU
  k_gemm<3><<<dim3(64, 2, 1), 256, 0, stream>>>((const unsigned short*)(ws + OFF_ADDNB),
                                                (const unsigned short*)(ws + OFF_W1B),
                                                ws + OFF_H1, b1, nullptr, 8192, 256, 256, 0, 0, 0);
  // FFN2 + bias + residual(addnormed)
  k_gemm<2><<<dim3(64, 2, 1), 256, 0, stream>>>((const unsigned short*)(ws + OFF_H1),
                                                (const unsigned short*)(ws + OFF_W2B),
                                                ws + OFF_H2, b2,
                                                (const float*)(ws + OFF_ADDNF),
                                                8192, 256, 256, 0, 0, 0);
  k_ln<1><<<2048, 256, 0, stream>>>((const float*)(ws + OFF_H2), ln_g, ln_b,
                                    (float*)(ws + OFF_Y1), nullptr);
  k_transout<<<dim3(8, 32, 8), 256, 0, stream>>>((const float*)(ws + OFF_Y1), (float*)d_out);
}

// Round 2
// 277.350 us; speedup vs baseline: 1.0674x; 1.0674x over previous
//
#include <hip/hip_runtime.h>
#include <stdint.h>

typedef __attribute__((ext_vector_type(8))) short short8;
typedef __attribute__((ext_vector_type(4))) float f32x4;

#define DEVI __device__ __forceinline__

DEVI unsigned short f2bf(float f) {
  union { float f; uint32_t u; } v; v.f = f;
  return (unsigned short)((v.u + 0x7fffu + ((v.u >> 16) & 1u)) >> 16);
}

DEVI void gload_lds16(const void* g, void* l) {
  __builtin_amdgcn_global_load_lds(
      (const __attribute__((address_space(1))) uint32_t*)g,
      (__attribute__((address_space(3))) uint32_t*)l, 16, 0, 0);
}

// ---------------- K0: positional encoding table T[256][32] ----------------
__global__ void k_petab(float* __restrict__ T) {
  int c = threadIdx.x;  // 256 threads
  int idx = ((c >= 128) ? c - 128 : c) >> 1;
  float freq = expf(-(float)idx * (logf(10000.0f) / 64.0f));
  for (int p = 0; p < 32; ++p) {
    float ang = (float)p * freq;
    T[c * 32 + p] = (c & 1) ? cosf(ang) : sinf(ang);
  }
}

// ---------------- K1: xpT = (x + pe) transposed to [b*1024+n][256], f32 + bf16 ----------------
__global__ __launch_bounds__(256) void k_xpt(const float* __restrict__ x,
                                             const float* __restrict__ T,
                                             unsigned short* __restrict__ xpt_bf,
                                             float* __restrict__ xpt_f) {
  __shared__ __align__(16) float tile[32][36];  // [n][c]
  const int b = blockIdx.z, c0 = blockIdx.x * 32, n0 = blockIdx.y * 32;
  const int t = threadIdx.x;
  {
    const int cl = t >> 3, ng = (t & 7) * 4;
    const int c = c0 + cl;
    float4 v = *(const float4*)(x + ((size_t)b * 256 + c) * 1024 + n0 + ng);
    float p0, p1, p2, p3;
    if (c < 128) {  // depends on w = n&31
      p0 = T[c * 32 + ng + 0]; p1 = T[c * 32 + ng + 1];
      p2 = T[c * 32 + ng + 2]; p3 = T[c * 32 + ng + 3];
    } else {        // depends on h = n>>5 (uniform over the 32-wide n-tile)
      p0 = p1 = p2 = p3 = T[c * 32 + (n0 >> 5)];
    }
    tile[ng + 0][cl] = v.x + p0;
    tile[ng + 1][cl] = v.y + p1;
    tile[ng + 2][cl] = v.z + p2;
    tile[ng + 3][cl] = v.w + p3;
  }
  __syncthreads();
  {
    const int nl = t >> 3, cg = (t & 7) * 4;
    float o0 = tile[nl][cg + 0], o1 = tile[nl][cg + 1];
    float o2 = tile[nl][cg + 2], o3 = tile[nl][cg + 3];
    size_t row = (size_t)b * 1024 + n0 + nl;
    *(float4*)(xpt_f + row * 256 + c0 + cg) = make_float4(o0, o1, o2, o3);
    uint32_t lo = (uint32_t)f2bf(o0) | ((uint32_t)f2bf(o1) << 16);
    uint32_t hi = (uint32_t)f2bf(o2) | ((uint32_t)f2bf(o3) << 16);
    *(uint2*)(xpt_bf + row * 256 + c0 + cg) = make_uint2(lo, hi);
  }
}

// ---------------- K2: pack conv weights -> Wpack[1536][2304] bf16, k = (kh*3+kw)*256 + ci ----------------
__global__ void k_packw(const float* __restrict__ Wk, const float* __restrict__ Wq,
                        const float* __restrict__ Wv, unsigned short* __restrict__ Wpack) {
  int i = blockIdx.x * 256 + threadIdx.x;
  if (i >= 1536 * 2304) return;
  int o = i / 2304, kn = i % 2304;
  int ci = kn & 255, khw = kn >> 8;  // 2304 = 9*256
  const float* src = (o < 512) ? Wk : ((o < 1024) ? Wq : Wv);
  int oo = o & 511;
  Wpack[i] = f2bf(src[((size_t)oo * 256 + ci) * 9 + khw]);
}

// ---------------- K3: misc packs (bias concat, permuted Wproj, W1/W2 casts) ----------------
__global__ void k_packmisc(const float* __restrict__ bk, const float* __restrict__ bq,
                           const float* __restrict__ bv, const float* __restrict__ Wproj,
                           const float* __restrict__ W1, const float* __restrict__ W2,
                           float* __restrict__ bias_kqv, unsigned short* __restrict__ WprojP,
                           unsigned short* __restrict__ W1b, unsigned short* __restrict__ W2b) {
  int i = blockIdx.x * 256 + threadIdx.x;  // 512*256 = 131072 threads
  if (i < 1536)
    bias_kqv[i] = (i < 512) ? bk[i] : ((i < 1024) ? bq[i - 512] : bv[i - 1024]);
  if (i < 131072) {
    int j = i >> 9, f = i & 511;
    int h = f >> 6, c = f & 63;
    WprojP[i] = f2bf(Wproj[(size_t)j * 512 + c * 8 + h]);  // fold att reshape (c*8+h) into weight
  }
  if (i < 65536) {
    W1b[i] = f2bf(W1[i]);
    W2b[i] = f2bf(W2[i]);
  }
}

// ---------------- K4: im2col -> xcolT[b*1024+n][2304] bf16 ----------------
__global__ __launch_bounds__(256) void k_im2col(const unsigned short* __restrict__ xpt_bf,
                                                unsigned short* __restrict__ xcol) {
  const int b = blockIdx.y;
  int t = blockIdx.x * 256 + threadIdx.x;  // < 1024*9*32
  int ci8 = t & 31;
  int rest = t >> 5;
  int khw = rest % 9;
  int n = rest / 9;
  int y = n >> 5, xq = n & 31;
  int ky = y + khw / 3 - 1, kx = xq + khw % 3 - 1;
  uint4 val = make_uint4(0u, 0u, 0u, 0u);
  if (ky >= 0 && ky < 32 && kx >= 0 && kx < 32)
    val = *(const uint4*)&xpt_bf[((size_t)b * 1024 + ky * 32 + kx) * 256 + ci8 * 8];
  *(uint4*)&xcol[((size_t)b * 1024 + n) * 2304 + khw * 256 + ci8 * 8] = val;
}

// ---------------- GEMM: C[M][N] = A[M][K] * B[N][K]^T  (both K-major bf16, f32 acc) ----------------
template <int EPI>
__global__ __launch_bounds__(256) void k_gemm(const unsigned short* __restrict__ A,
                                              const unsigned short* __restrict__ B,
                                              void* __restrict__ Cout,
                                              const float* __restrict__ bias,
                                              const float* __restrict__ resid,
                                              int M, int N, int K,
                                              size_t aBatch, size_t bBatch, size_t cBatch) {
  __shared__ __align__(16) unsigned short As[128 * 64];
  __shared__ __align__(16) unsigned short Bs[128 * 64];
  const int tid = threadIdx.x, l = tid & 63, w = tid >> 6;
  const int wm = w >> 1, wn = w & 1;
  const int m0 = blockIdx.x * 128, n0 = blockIdx.y * 128;
  const int bz = blockIdx.z;
  const char* Ab = (const char*)(A + (size_t)bz * aBatch);
  const char* Bb = (const char*)(B + (size_t)bz * bBatch);

  f32x4 acc[4][4] = {};

  for (int kt = 0; kt < K; kt += 64) {
#pragma unroll
    for (int j = 0; j < 4; ++j) {
      int seg = w * 4 + j;
      int r8 = seg * 8 + (l >> 3);
      int cb = (l & 7) * 16;
      gload_lds16(Ab + ((size_t)(m0 + r8) * K + kt) * 2 + cb, (char*)As + seg * 1024);
      gload_lds16(Bb + ((size_t)(n0 + r8) * K + kt) * 2 + cb, (char*)Bs + seg * 1024);
    }
    __syncthreads();
#pragma unroll
    for (int kk = 0; kk < 2; ++kk) {
      short8 af[4], bfr[4];
#pragma unroll
      for (int fm = 0; fm < 4; ++fm)
        af[fm] = *(const short8*)((const char*)As +
                                  (wm * 64 + fm * 16 + (l & 15)) * 128 + kk * 64 + (l >> 4) * 16);
#pragma unroll
      for (int fn = 0; fn < 4; ++fn)
        bfr[fn] = *(const short8*)((const char*)Bs +
                                   (wn * 64 + fn * 16 + (l & 15)) * 128 + kk * 64 + (l >> 4) * 16);
#pragma unroll
      for (int fm = 0; fm < 4; ++fm)
#pragma unroll
        for (int fn = 0; fn < 4; ++fn)
          acc[fm][fn] = __builtin_amdgcn_mfma_f32_16x16x32_bf16(af[fm], bfr[fn], acc[fm][fn], 0, 0, 0);
    }
    __syncthreads();
  }

#pragma unroll
  for (int fm = 0; fm < 4; ++fm)
#pragma unroll
    for (int fn = 0; fn < 4; ++fn)
#pragma unroll
      for (int r = 0; r < 4; ++r) {
        int row = m0 + wm * 64 + fm * 16 + (l >> 4) * 4 + r;
        int col = n0 + wn * 64 + fn * 16 + (l & 15);
        float v = acc[fm][fn][r];
        size_t cidx = (size_t)bz * cBatch + (size_t)row * N + col;
        if (EPI == 0) {
          v += bias[col];
          ((unsigned short*)Cout)[cidx] = f2bf(v);
        } else if (EPI == 1) {
          v += bias[row];
          ((unsigned short*)Cout)[cidx] = f2bf(v);
        } else if (EPI == 2) {
          v += bias[col] + resid[(size_t)row * N + col];
          ((float*)Cout)[cidx] = v;
        } else {
          v += bias[col];
          v = (v > 0.f) ? v : 0.1f * v;
          ((unsigned short*)Cout)[cidx] = f2bf(v);
        }
      }
}

// ---------------- K5: fused attention v2 ----------------
// Head-axis softmax => no coupling along m: split-K over m (2 chunks).
// 512 blocks: id = b(&7, XCD-local) + 8*ntile(32) + 256*chunk(2).
// 8 waves = 8 heads. Q/V fragments direct from global (L2), register-prefetched.
// LDS: S[8][32][36] f32 (padded) + P[8][32][40] bf16 (80B rows, bank-balanced).
__global__ __launch_bounds__(512, 4) void k_attn(const unsigned short* __restrict__ kq_t,
                                                 const unsigned short* __restrict__ v,
                                                 float* __restrict__ part) {
  __shared__ __align__(16) float Ss[8][32][36];
  __shared__ __align__(16) unsigned short Ps[8][32][40];
  const int tid = threadIdx.x, l = tid & 63, h = tid >> 6;
  const int id = blockIdx.x;
  const int bb = id & 7;
  const int n0 = ((id >> 3) & 31) * 32;
  const int ch = id >> 8;
  const int m_base = ch * 512;
  const size_t kqBase = (size_t)bb * 1024 * 1024;
  const size_t vBase = (size_t)bb * 512 * 1024;

  // K fragments (A operand), resident all kernel.
  short8 ak[2][2];
#pragma unroll
  for (int fn = 0; fn < 2; ++fn)
#pragma unroll
    for (int kk = 0; kk < 2; ++kk)
      ak[fn][kk] = *(const short8*)&kq_t[kqBase + (size_t)(n0 + fn * 16 + (l & 15)) * 1024 +
                                         h * 64 + kk * 32 + (l >> 4) * 8];

  short8 qf[2][2];  // [fm][kk] Q fragments (B operand), prefetched
  short8 vf[4];     // [fc]     V fragments (B operand), prefetched

#define LOADQ(m0_)                                                                     \
  {                                                                                    \
    _Pragma("unroll") for (int fm = 0; fm < 2; ++fm)                                   \
        _Pragma("unroll") for (int kk = 0; kk < 2; ++kk)                               \
            qf[fm][kk] = *(const short8*)&kq_t[kqBase +                                \
                (size_t)((m0_) + fm * 16 + (l & 15)) * 1024 + 512 +                    \
                h * 64 + kk * 32 + (l >> 4) * 8];                                      \
  }
#define LOADV(m0_)                                                                     \
  {                                                                                    \
    _Pragma("unroll") for (int fc = 0; fc < 4; ++fc)                                   \
        vf[fc] = *(const short8*)&v[vBase + (size_t)(h * 64 + fc * 16 + (l & 15)) * 1024 + \
                                    (m0_) + (l >> 4) * 8];                             \
  }

  LOADQ(m_base);
  LOADV(m_base);

  f32x4 oacc[2][4] = {};

  for (int it = 0; it < 16; ++it) {
    const int m0 = m_base + it * 32;
    const int m1 = (it < 15) ? (m0 + 32) : m0;

    // --- QK^T: S[n'][m'] for this head ---
    f32x4 s[2][2] = {};
#pragma unroll
    for (int kk = 0; kk < 2; ++kk)
#pragma unroll
      for (int fn = 0; fn < 2; ++fn)
#pragma unroll
        for (int fm = 0; fm < 2; ++fm)
          s[fn][fm] = __builtin_amdgcn_mfma_f32_16x16x32_bf16(ak[fn][kk], qf[fm][kk], s[fn][fm], 0, 0, 0);

    LOADQ(m1);  // prefetch next-iter Q (WAR on qf is register-renamed by compiler)

#pragma unroll
    for (int fn = 0; fn < 2; ++fn)
#pragma unroll
      for (int fm = 0; fm < 2; ++fm)
#pragma unroll
        for (int r = 0; r < 4; ++r) {
          int np = fn * 16 + (l >> 4) * 4 + r;
          int mp = fm * 16 + (l & 15);
          Ss[h][np][mp] = s[fn][fm][r] * (1.0f / 1024.0f);
        }
    __syncthreads();

    // --- softmax over heads: each thread owns 2 consecutive m at one n ---
    {
      const int n = tid >> 4;
      const int m2 = (tid & 15) * 2;
      float a[8], b[8];
      float mx0 = -1e30f, mx1 = -1e30f;
#pragma unroll
      for (int hh = 0; hh < 8; ++hh) {
        float2 e = *(const float2*)&Ss[hh][n][m2];
        a[hh] = e.x; b[hh] = e.y;
        mx0 = fmaxf(mx0, e.x); mx1 = fmaxf(mx1, e.y);
      }
      float s0 = 0.f, s1 = 0.f;
#pragma unroll
      for (int hh = 0; hh < 8; ++hh) {
        a[hh] = __expf(a[hh] - mx0); s0 += a[hh];
        b[hh] = __expf(b[hh] - mx1); s1 += b[hh];
      }
      float i0 = 1.0f / s0, i1 = 1.0f / s1;
#pragma unroll
      for (int hh = 0; hh < 8; ++hh) {
        uint32_t pk = (uint32_t)f2bf(a[hh] * i0) | ((uint32_t)f2bf(b[hh] * i1) << 16);
        *(uint32_t*)&Ps[hh][n][m2] = pk;
      }
    }
    __syncthreads();

    // --- P @ V^T accumulate ---
    short8 ap[2];
#pragma unroll
    for (int fn = 0; fn < 2; ++fn)
      ap[fn] = *(const short8*)&Ps[h][fn * 16 + (l & 15)][(l >> 4) * 8];
#pragma unroll
    for (int fc = 0; fc < 4; ++fc)
#pragma unroll
      for (int fn = 0; fn < 2; ++fn)
        oacc[fn][fc] = __builtin_amdgcn_mfma_f32_16x16x32_bf16(ap[fn], vf[fc], oacc[fn][fc], 0, 0, 0);

    LOADV(m1);  // prefetch next-iter V
  }

  // partial O (f32) for this m-chunk
#pragma unroll
  for (int fn = 0; fn < 2; ++fn)
#pragma unroll
    for (int fc = 0; fc < 4; ++fc)
#pragma unroll
      for (int r = 0; r < 4; ++r) {
        int np = n0 + fn * 16 + (l >> 4) * 4 + r;
        int c = h * 64 + fc * 16 + (l & 15);
        part[(size_t)ch * 8192 * 512 + ((size_t)bb * 1024 + np) * 512 + c] = oacc[fn][fc][r];
      }
#undef LOADQ
#undef LOADV
}

// ---------------- K5b: reduce the two m-chunk partials -> att bf16 ----------------
__global__ __launch_bounds__(256) void k_reduce(const float* __restrict__ part,
                                                unsigned short* __restrict__ att) {
  size_t i = ((size_t)blockIdx.x * 256 + threadIdx.x) * 4;  // 4 f32 per thread
  float4 p0 = *(const float4*)&part[i];
  float4 p1 = *(const float4*)&part[(size_t)8192 * 512 + i];
  uint32_t lo = (uint32_t)f2bf(p0.x + p1.x) | ((uint32_t)f2bf(p0.y + p1.y) << 16);
  uint32_t hi = (uint32_t)f2bf(p0.z + p1.z) | ((uint32_t)f2bf(p0.w + p1.w) << 16);
  *(uint2*)&att[i] = make_uint2(lo, hi);
}

// ---------------- K6: LayerNorm over rows of [8192][256] ----------------
template <int MODE>
__global__ __launch_bounds__(256) void k_ln(const float* __restrict__ in,
                                            const float* __restrict__ g,
                                            const float* __restrict__ bta,
                                            float* __restrict__ out_f,
                                            unsigned short* __restrict__ out_b) {
  const int l = threadIdx.x & 63, w = threadIdx.x >> 6;
  const size_t row = (size_t)blockIdx.x * 4 + w;
  float4 xv = *(const float4*)(in + row * 256 + l * 4);
  float s = xv.x + xv.y + xv.z + xv.w;
  float q = xv.x * xv.x + xv.y * xv.y + xv.z * xv.z + xv.w * xv.w;
#pragma unroll
  for (int o = 1; o < 64; o <<= 1) {
    s += __shfl_xor(s, o, 64);
    q += __shfl_xor(q, o, 64);
  }
  float mu = s * (1.0f / 256.0f);
  float var = q * (1.0f / 256.0f) - mu * mu;
  float rstd = rsqrtf(var + 1e-5f);
  float4 gv = *(const float4*)(g + l * 4);
  float4 bv = *(const float4*)(bta + l * 4);
  float o0 = (xv.x - mu) * rstd * gv.x + bv.x;
  float o1 = (xv.y - mu) * rstd * gv.y + bv.y;
  float o2 = (xv.z - mu) * rstd * gv.z + bv.z;
  float o3 = (xv.w - mu) * rstd * gv.w + bv.w;
  *(float4*)(out_f + row * 256 + l * 4) = make_float4(o0, o1, o2, o3);
  if (MODE == 0) {
    uint32_t lo = (uint32_t)f2bf(o0) | ((uint32_t)f2bf(o1) << 16);
    uint32_t hi = (uint32_t)f2bf(o2) | ((uint32_t)f2bf(o3) << 16);
    *(uint2*)(out_b + row * 256 + l * 4) = make_uint2(lo, hi);
  }
}

// ---------------- K7: transpose [b*1024+n][256] -> d_out [b][256][1024] ----------------
__global__ __launch_bounds__(256) void k_transout(const float* __restrict__ in,
                                                  float* __restrict__ out) {
  __shared__ __align__(16) float tile[32][36];  // [c][n]
  const int b = blockIdx.z, c0 = blockIdx.x * 32, n0 = blockIdx.y * 32;
  const int t = threadIdx.x;
  {
    const int nl = t >> 3, cg = (t & 7) * 4;
    float4 v = *(const float4*)(in + ((size_t)b * 1024 + n0 + nl) * 256 + c0 + cg);
    tile[cg + 0][nl] = v.x;
    tile[cg + 1][nl] = v.y;
    tile[cg + 2][nl] = v.z;
    tile[cg + 3][nl] = v.w;
  }
  __syncthreads();
  {
    const int cl = t >> 3, ng = (t & 7) * 4;
    float4 o = make_float4(tile[cl][ng + 0], tile[cl][ng + 1], tile[cl][ng + 2], tile[cl][ng + 3]);
    *(float4*)(out + ((size_t)b * 256 + c0 + cl) * 1024 + n0 + ng) = o;
  }
}

// ---------------- host launcher ----------------
extern "C" void kernel_launch(void* const* d_in, const int* in_sizes, int n_in,
                              void* d_out, int out_size, void* d_ws, size_t ws_size,
                              hipStream_t stream) {
  const float* x     = (const float*)d_in[0];
  const float* Wk    = (const float*)d_in[1];
  const float* bk    = (const float*)d_in[2];
  const float* Wq    = (const float*)d_in[3];
  const float* bq    = (const float*)d_in[4];
  const float* Wv    = (const float*)d_in[5];
  const float* bv    = (const float*)d_in[6];
  const float* Wproj = (const float*)d_in[7];
  const float* bproj = (const float*)d_in[8];
  const float* ln_g  = (const float*)d_in[9];
  const float* ln_b  = (const float*)d_in[10];
  const float* W1    = (const float*)d_in[11];
  const float* b1    = (const float*)d_in[12];
  const float* W2    = (const float*)d_in[13];
  const float* b2    = (const float*)d_in[14];

  char* ws = (char*)d_ws;
  constexpr size_t OFF_XPTB  = 0;                                    // bf16 [8192][256]
  constexpr size_t OFF_XPTF  = OFF_XPTB  + (size_t)8192 * 256 * 2;   // f32  [8192][256]
  constexpr size_t OFF_WPACK = OFF_XPTF  + (size_t)8192 * 256 * 4;   // bf16 [1536][2304]
  constexpr size_t OFF_BIAS  = OFF_WPACK + (size_t)1536 * 2304 * 2;  // f32  [1536]
  constexpr size_t OFF_WPROJ = OFF_BIAS  + (size_t)1536 * 4;         // bf16 [256][512]
  constexpr size_t OFF_W1B   = OFF_WPROJ + (size_t)256 * 512 * 2;    // bf16 [256][256]
  constexpr size_t OFF_W2B   = OFF_W1B   + (size_t)256 * 256 * 2;    // bf16 [256][256]
  constexpr size_t OFF_PET   = OFF_W2B   + (size_t)256 * 256 * 2;    // f32  [256][32]
  constexpr size_t OFF_KQT   = OFF_PET   + (size_t)256 * 32 * 4;     // bf16 [8192][1024]
  constexpr size_t OFF_V     = OFF_KQT   + (size_t)8192 * 1024 * 2;  // bf16 [8][512][1024]
  constexpr size_t OFF_ATT   = OFF_V     + (size_t)8 * 512 * 1024 * 2; // bf16 [8192][512]
  constexpr size_t OFF_X     = OFF_ATT   + (size_t)8192 * 512 * 2;
  // region X: im2col during convs, then attn partials, then FFN-phase buffers
  constexpr size_t OFF_XCOL  = OFF_X;                                // bf16 [8192][2304]
  constexpr size_t OFF_PART  = OFF_X;                                // f32  [2][8192][512]
  constexpr size_t OFF_Y1    = OFF_X;                                // f32 [8192][256]
  constexpr size_t OFF_ADDNF = OFF_Y1    + (size_t)8192 * 256 * 4;   // f32
  constexpr size_t OFF_ADDNB = OFF_ADDNF + (size_t)8192 * 256 * 4;   // bf16
  constexpr size_t OFF_H1    = OFF_ADDNB + (size_t)8192 * 256 * 2;   // bf16
  constexpr size_t OFF_H2    = OFF_H1    + (size_t)8192 * 256 * 2;   // f32

  (void)in_sizes; (void)n_in; (void)out_size; (void)ws_size;

  k_petab<<<1, 256, 0, stream>>>((float*)(ws + OFF_PET));
  k_xpt<<<dim3(8, 32, 8), 256, 0, stream>>>(x, (const float*)(ws + OFF_PET),
                                            (unsigned short*)(ws + OFF_XPTB),
                                            (float*)(ws + OFF_XPTF));
  k_packw<<<(1536 * 2304 + 255) / 256, 256, 0, stream>>>(Wk, Wq, Wv,
                                                         (unsigned short*)(ws + OFF_WPACK));
  k_packmisc<<<512, 256, 0, stream>>>(bk, bq, bv, Wproj, W1, W2,
                                      (float*)(ws + OFF_BIAS),
                                      (unsigned short*)(ws + OFF_WPROJ),
                                      (unsigned short*)(ws + OFF_W1B),
                                      (unsigned short*)(ws + OFF_W2B));
  k_im2col<<<dim3(1152, 8), 256, 0, stream>>>((const unsigned short*)(ws + OFF_XPTB),
                                              (unsigned short*)(ws + OFF_XCOL));
  // conv K+Q: C[n][o] = xcol[n][k] . Wkq[o][k]   (M=8192, N=1024, K=2304)
  k_gemm<0><<<dim3(64, 8, 1), 256, 0, stream>>>((const unsigned short*)(ws + OFF_XCOL),
                                                (const unsigned short*)(ws + OFF_WPACK),
                                                ws + OFF_KQT, (const float*)(ws + OFF_BIAS),
                                                nullptr, 8192, 1024, 2304, 0, 0, 0);
  // conv V: C[o][m] = Wv[o][k] . xcol[m][k]      (M=512, N=1024, K=2304, batched over b)
  k_gemm<1><<<dim3(4, 8, 8), 256, 0, stream>>>((const unsigned short*)(ws + OFF_WPACK) + (size_t)1024 * 2304,
                                               (const unsigned short*)(ws + OFF_XCOL),
                                               ws + OFF_V, (const float*)(ws + OFF_BIAS) + 1024,
                                               nullptr, 512, 1024, 2304,
                                               0, (size_t)1024 * 2304, (size_t)512 * 1024);
  // fused attention (split-m over 2 chunks) + reduce
  k_attn<<<dim3(512), 512, 0, stream>>>((const unsigned short*)(ws + OFF_KQT),
                                        (const unsigned short*)(ws + OFF_V),
                                        (float*)(ws + OFF_PART));
  k_reduce<<<dim3(4096), 256, 0, stream>>>((const float*)(ws + OFF_PART),
                                           (unsigned short*)(ws + OFF_ATT));
  // attproj + bias + residual(x+pe): y1 f32      (M=8192, N=256, K=512)
  k_gemm<2><<<dim3(64, 2, 1), 256, 0, stream>>>((const unsigned short*)(ws + OFF_ATT),
                                                (const unsigned short*)(ws + OFF_WPROJ),
                                                ws + OFF_Y1, bproj,
                                                (const float*)(ws + OFF_XPTF),
                                                8192, 256, 512, 0, 0, 0);
  k_ln<0><<<2048, 256, 0, stream>>>((const float*)(ws + OFF_Y1), ln_g, ln_b,
                                    (float*)(ws + OFF_ADDNF), (unsigned short*)(ws + OFF_ADDNB));
  // FFN1 + LeakyReLU
  k_gemm<3><<<dim3(64, 2, 1), 256, 0, stream>>>((const unsigned short*)(ws + OFF_ADDNB),
                                                (const unsigned short*)(ws + OFF_W1B),
                                                ws + OFF_H1, b1, nullptr, 8192, 256, 256, 0, 0, 0);
  // FFN2 + bias + residual(addnormed)
  k_gemm<2><<<dim3(64, 2, 1), 256, 0, stream>>>((const unsigned short*)(ws + OFF_H1),
                                                (const unsigned short*)(ws + OFF_W2B),
                                                ws + OFF_H2, b2,
                                                (const float*)(ws + OFF_ADDNF),
                                                8192, 256, 256, 0, 0, 0);
  k_ln<1><<<2048, 256, 0, stream>>>((const float*)(ws + OFF_H2), ln_g, ln_b,
                                    (float*)(ws + OFF_Y1), nullptr);
  k_transout<<<dim3(8, 32, 8), 256, 0, stream>>>((const float*)(ws + OFF_Y1), (float*)d_out);
}

// Round 3
// 259.388 us; speedup vs baseline: 1.1413x; 1.0692x over previous
//
#include <hip/hip_runtime.h>
#include <stdint.h>

typedef __attribute__((ext_vector_type(8))) short short8;
typedef __attribute__((ext_vector_type(4))) float f32x4;

#define DEVI __device__ __forceinline__

DEVI unsigned short f2bf(float f) {
  union { float f; uint32_t u; } v; v.f = f;
  return (unsigned short)((v.u + 0x7fffu + ((v.u >> 16) & 1u)) >> 16);
}

DEVI float bf2f(uint32_t hi16) {  // hi16 already in bits [31:16]
  union { uint32_t u; float f; } v; v.u = hi16;
  return v.f;
}

DEVI void gload_lds16(const void* g, void* l) {
  __builtin_amdgcn_global_load_lds(
      (const __attribute__((address_space(1))) uint32_t*)g,
      (__attribute__((address_space(3))) uint32_t*)l, 16, 0, 0);
}

// ---------------- K0: positional encoding table T[256][32] + zero page ----------------
__global__ void k_petab(float* __restrict__ T, float* __restrict__ zp) {
  int c = threadIdx.x;  // 256 threads
  if (c < 64) zp[c] = 0.0f;
  int idx = ((c >= 128) ? c - 128 : c) >> 1;
  float freq = expf(-(float)idx * (logf(10000.0f) / 64.0f));
  for (int p = 0; p < 32; ++p) {
    float ang = (float)p * freq;
    T[c * 32 + p] = (c & 1) ? cosf(ang) : sinf(ang);
  }
}

// ---------------- K1: xpT = (x + pe) transposed to [b*1024+n][256], f32 + bf16 ----------------
__global__ __launch_bounds__(256) void k_xpt(const float* __restrict__ x,
                                             const float* __restrict__ T,
                                             unsigned short* __restrict__ xpt_bf,
                                             float* __restrict__ xpt_f) {
  __shared__ __align__(16) float tile[32][36];  // [n][c]
  const int b = blockIdx.z, c0 = blockIdx.x * 32, n0 = blockIdx.y * 32;
  const int t = threadIdx.x;
  {
    const int cl = t >> 3, ng = (t & 7) * 4;
    const int c = c0 + cl;
    float4 v = *(const float4*)(x + ((size_t)b * 256 + c) * 1024 + n0 + ng);
    float p0, p1, p2, p3;
    if (c < 128) {  // depends on w = n&31
      p0 = T[c * 32 + ng + 0]; p1 = T[c * 32 + ng + 1];
      p2 = T[c * 32 + ng + 2]; p3 = T[c * 32 + ng + 3];
    } else {        // depends on h = n>>5 (uniform over the 32-wide n-tile)
      p0 = p1 = p2 = p3 = T[c * 32 + (n0 >> 5)];
    }
    tile[ng + 0][cl] = v.x + p0;
    tile[ng + 1][cl] = v.y + p1;
    tile[ng + 2][cl] = v.z + p2;
    tile[ng + 3][cl] = v.w + p3;
  }
  __syncthreads();
  {
    const int nl = t >> 3, cg = (t & 7) * 4;
    float o0 = tile[nl][cg + 0], o1 = tile[nl][cg + 1];
    float o2 = tile[nl][cg + 2], o3 = tile[nl][cg + 3];
    size_t row = (size_t)b * 1024 + n0 + nl;
    *(float4*)(xpt_f + row * 256 + c0 + cg) = make_float4(o0, o1, o2, o3);
    uint32_t lo = (uint32_t)f2bf(o0) | ((uint32_t)f2bf(o1) << 16);
    uint32_t hi = (uint32_t)f2bf(o2) | ((uint32_t)f2bf(o3) << 16);
    *(uint2*)(xpt_bf + row * 256 + c0 + cg) = make_uint2(lo, hi);
  }
}

// ---------------- K2: pack conv weights -> Wpack[1536][2304] bf16, k = (kh*3+kw)*256 + ci ----------------
__global__ void k_packw(const float* __restrict__ Wk, const float* __restrict__ Wq,
                        const float* __restrict__ Wv, unsigned short* __restrict__ Wpack) {
  int i = blockIdx.x * 256 + threadIdx.x;
  if (i >= 1536 * 2304) return;
  int o = i / 2304, kn = i % 2304;
  int ci = kn & 255, khw = kn >> 8;  // 2304 = 9*256
  const float* src = (o < 512) ? Wk : ((o < 1024) ? Wq : Wv);
  int oo = o & 511;
  Wpack[i] = f2bf(src[((size_t)oo * 256 + ci) * 9 + khw]);
}

// ---------------- K3: misc packs (bias concat, permuted Wproj, W1/W2 casts) ----------------
__global__ void k_packmisc(const float* __restrict__ bk, const float* __restrict__ bq,
                           const float* __restrict__ bv, const float* __restrict__ Wproj,
                           const float* __restrict__ W1, const float* __restrict__ W2,
                           float* __restrict__ bias_kqv, unsigned short* __restrict__ WprojP,
                           unsigned short* __restrict__ W1b, unsigned short* __restrict__ W2b) {
  int i = blockIdx.x * 256 + threadIdx.x;  // 512*256 = 131072 threads
  if (i < 1536)
    bias_kqv[i] = (i < 512) ? bk[i] : ((i < 1024) ? bq[i - 512] : bv[i - 1024]);
  if (i < 131072) {
    int j = i >> 9, f = i & 511;
    int h = f >> 6, c = f & 63;
    WprojP[i] = f2bf(Wproj[(size_t)j * 512 + c * 8 + h]);  // fold att reshape (c*8+h) into weight
  }
  if (i < 65536) {
    W1b[i] = f2bf(W1[i]);
    W2b[i] = f2bf(W2[i]);
  }
}

// ---------------- implicit-im2col source address ----------------
// row r_loc of the virtual xcol matrix (k-order (khw)*256+ci), K-step offset kt.
DEVI const char* imp_src(const char* base, int r_loc, int dy, int dx, int ci,
                         const char* zp) {
  int nl = r_loc & 1023, pg = r_loc >> 10;
  int y = (nl >> 5) + dy, xx = (nl & 31) + dx;
  const char* s = base + ((((size_t)pg << 10) + y * 32 + xx) * 256 + ci) * 2;
  return (((unsigned)y < 32u) && ((unsigned)xx < 32u)) ? s : zp;
}

// ---------------- GEMM: C[M][N] = A[M][K] * B[N][K]^T  (both K-major bf16, f32 acc) ----------------
// AIMP/BIMP: that side is the implicit-im2col of xpt_bf (base pointer = xpt batch base).
// EPI 0: bf16 out, + bias[col]                (conv K,Q -> kq_t)
// EPI 1: bf16 out, + bias[row]                (conv V -> v)
// EPI 2: f32 out,  + bias[col] + resid[row*N+col]   (attproj / FFN2)
// EPI 3: bf16 out, + bias[col], LeakyReLU(0.1)      (FFN1)
template <int EPI, bool AIMP, bool BIMP>
__global__ __launch_bounds__(256) void k_gemm(const unsigned short* __restrict__ A,
                                              const unsigned short* __restrict__ B,
                                              void* __restrict__ Cout,
                                              const float* __restrict__ bias,
                                              const float* __restrict__ resid,
                                              const char* __restrict__ zp,
                                              int M, int N, int K,
                                              size_t aBatch, size_t bBatch, size_t cBatch) {
  __shared__ __align__(16) unsigned short As[128 * 64];
  __shared__ __align__(16) unsigned short Bs[128 * 64];
  const int tid = threadIdx.x, l = tid & 63, w = tid >> 6;
  const int wm = w >> 1, wn = w & 1;
  const int m0 = blockIdx.x * 128, n0 = blockIdx.y * 128;
  const int bz = blockIdx.z;
  const char* Ab = (const char*)(A + (size_t)bz * aBatch);
  const char* Bb = (const char*)(B + (size_t)bz * bBatch);

  f32x4 acc[4][4] = {};

  for (int kt = 0; kt < K; kt += 64) {
    // scalar per K-step (khw uniform since 64 | 256)
    int khw = kt >> 8;
    int dy = khw / 3 - 1, dx = khw - (khw / 3) * 3 - 1;
    int ci = (kt & 255) + (l & 7) * 8;
#pragma unroll
    for (int j = 0; j < 4; ++j) {
      int seg = w * 4 + j;
      int r8 = seg * 8 + (l >> 3);
      int cb = (l & 7) * 16;
      const char* sa;
      if (AIMP) sa = imp_src(Ab, m0 + r8, dy, dx, ci, zp);
      else      sa = Ab + ((size_t)(m0 + r8) * K + kt) * 2 + cb;
      gload_lds16(sa, (char*)As + seg * 1024);
      const char* sb;
      if (BIMP) sb = imp_src(Bb, n0 + r8, dy, dx, ci, zp);
      else      sb = Bb + ((size_t)(n0 + r8) * K + kt) * 2 + cb;
      gload_lds16(sb, (char*)Bs + seg * 1024);
    }
    __syncthreads();
#pragma unroll
    for (int kk = 0; kk < 2; ++kk) {
      short8 af[4], bfr[4];
#pragma unroll
      for (int fm = 0; fm < 4; ++fm)
        af[fm] = *(const short8*)((const char*)As +
                                  (wm * 64 + fm * 16 + (l & 15)) * 128 + kk * 64 + (l >> 4) * 16);
#pragma unroll
      for (int fn = 0; fn < 4; ++fn)
        bfr[fn] = *(const short8*)((const char*)Bs +
                                   (wn * 64 + fn * 16 + (l & 15)) * 128 + kk * 64 + (l >> 4) * 16);
#pragma unroll
      for (int fm = 0; fm < 4; ++fm)
#pragma unroll
        for (int fn = 0; fn < 4; ++fn)
          acc[fm][fn] = __builtin_amdgcn_mfma_f32_16x16x32_bf16(af[fm], bfr[fn], acc[fm][fn], 0, 0, 0);
    }
    __syncthreads();
  }

#pragma unroll
  for (int fm = 0; fm < 4; ++fm)
#pragma unroll
    for (int fn = 0; fn < 4; ++fn)
#pragma unroll
      for (int r = 0; r < 4; ++r) {
        int row = m0 + wm * 64 + fm * 16 + (l >> 4) * 4 + r;
        int col = n0 + wn * 64 + fn * 16 + (l & 15);
        float v = acc[fm][fn][r];
        size_t cidx = (size_t)bz * cBatch + (size_t)row * N + col;
        if (EPI == 0) {
          v += bias[col];
          ((unsigned short*)Cout)[cidx] = f2bf(v);
        } else if (EPI == 1) {
          v += bias[row];
          ((unsigned short*)Cout)[cidx] = f2bf(v);
        } else if (EPI == 2) {
          v += bias[col] + resid[(size_t)row * N + col];
          ((float*)Cout)[cidx] = v;
        } else {
          v += bias[col];
          v = (v > 0.f) ? v : 0.1f * v;
          ((unsigned short*)Cout)[cidx] = f2bf(v);
        }
      }
}

// ---------------- K5: fused attention v3 — 1-barrier software-pipelined ----------------
// Head-axis softmax (no coupling along m) => split-m in 2 chunks of 512.
// 512 blocks: id = b(&7, XCD-local) + 8*ntile(32) + 256*chunk(2). 8 waves = 8 heads.
// Per 32-m step p: phase = { PV(p-2) | QK(p) -> Ss[p&1] | SM(p-1): Ss->Ps } + 1 barrier.
// S^T orientation (mfma(Q,K)): lane holds 4 consecutive m at fixed n -> bf16 m-pair pack.
// LDS: Ss[2][8][32][36] bf16 (36.9KB) + Ps[2][8][32][40] bf16 (40.9KB) -> 2 blocks/CU.
__global__ __launch_bounds__(512, 4) void k_attn(const unsigned short* __restrict__ kq_t,
                                                 const unsigned short* __restrict__ v,
                                                 float* __restrict__ part) {
  __shared__ unsigned short Ss[2][8][32][36];
  __shared__ unsigned short Ps[2][8][32][40];
  const int tid = threadIdx.x, l = tid & 63, h = tid >> 6;
  const int g = l >> 4, ln = l & 15;
  const int id = blockIdx.x;
  const int bb = id & 7;
  const int n0 = ((id >> 3) & 31) * 32;
  const int ch = id >> 8;
  const int m_base = ch * 512;
  const size_t kqBase = (size_t)bb * 1024 * 1024;
  const size_t vBase = (size_t)bb * 512 * 1024;

  // K fragments (B operand: col n, k-slice), resident all kernel.
  short8 ak[2][2];
#pragma unroll
  for (int fn = 0; fn < 2; ++fn)
#pragma unroll
    for (int kk = 0; kk < 2; ++kk)
      ak[fn][kk] = *(const short8*)&kq_t[kqBase + (size_t)(n0 + fn * 16 + ln) * 1024 +
                                         h * 64 + kk * 32 + g * 8];

  short8 qf[2][2];  // [msub][kk] Q fragments (A operand: row m)
  short8 vf[4];     // [fc]      V fragments (B operand: col c, k=m-slice)
  f32x4 oacc[2][4] = {};

#define LOADQ(S)                                                                        \
  {                                                                                     \
    int m0_ = m_base + (S) * 32;                                                        \
    _Pragma("unroll") for (int ms = 0; ms < 2; ++ms)                                    \
        _Pragma("unroll") for (int kk = 0; kk < 2; ++kk)                                \
            qf[ms][kk] = *(const short8*)&kq_t[kqBase +                                 \
                (size_t)(m0_ + ms * 16 + ln) * 1024 + 512 + h * 64 + kk * 32 + g * 8];  \
  }
#define LOADV(S)                                                                        \
  {                                                                                     \
    int m0_ = m_base + (S) * 32;                                                        \
    _Pragma("unroll") for (int fc = 0; fc < 4; ++fc)                                    \
        vf[fc] = *(const short8*)&v[vBase + (size_t)(h * 64 + fc * 16 + ln) * 1024 +    \
                                    m0_ + g * 8];                                       \
  }
// QK: S^T[m][n] = mfma(Q_m, K_n); pack to bf16 m-pairs, write b64 per (msub,fn)
#define QK(BUF)                                                                         \
  {                                                                                     \
    f32x4 s_[2][2] = {};                                                                \
    _Pragma("unroll") for (int kk = 0; kk < 2; ++kk)                                    \
        _Pragma("unroll") for (int ms = 0; ms < 2; ++ms)                                \
            _Pragma("unroll") for (int fn = 0; fn < 2; ++fn)                            \
                s_[ms][fn] = __builtin_amdgcn_mfma_f32_16x16x32_bf16(                   \
                    qf[ms][kk], ak[fn][kk], s_[ms][fn], 0, 0, 0);                       \
    _Pragma("unroll") for (int ms = 0; ms < 2; ++ms)                                    \
        _Pragma("unroll") for (int fn = 0; fn < 2; ++fn) {                              \
      uint32_t u0 = (uint32_t)f2bf(s_[ms][fn][0] * SC) |                                \
                    ((uint32_t)f2bf(s_[ms][fn][1] * SC) << 16);                         \
      uint32_t u1 = (uint32_t)f2bf(s_[ms][fn][2] * SC) |                                \
                    ((uint32_t)f2bf(s_[ms][fn][3] * SC) << 16);                         \
      *(uint2*)&Ss[BUF][h][fn * 16 + ln][ms * 16 + 4 * g] = make_uint2(u0, u1);         \
    }                                                                                   \
  }
// SM: softmax over the 8 heads; thread owns (n = tid>>4, m-pair = tid&15)
#define SM(BUF)                                                                         \
  {                                                                                     \
    const int n_ = tid >> 4, mp_ = (tid & 15) * 2;                                      \
    float a0[8], a1[8];                                                                 \
    float mx0 = -1e30f, mx1 = -1e30f;                                                   \
    _Pragma("unroll") for (int hh = 0; hh < 8; ++hh) {                                  \
      uint32_t u = *(const uint32_t*)&Ss[BUF][hh][n_][mp_];                             \
      a0[hh] = bf2f(u << 16);                                                           \
      a1[hh] = bf2f(u & 0xffff0000u);                                                   \
      mx0 = fmaxf(mx0, a0[hh]); mx1 = fmaxf(mx1, a1[hh]);                               \
    }                                                                                   \
    float s0 = 0.f, s1 = 0.f;                                                           \
    _Pragma("unroll") for (int hh = 0; hh < 8; ++hh) {                                  \
      a0[hh] = __expf(a0[hh] - mx0); s0 += a0[hh];                                      \
      a1[hh] = __expf(a1[hh] - mx1); s1 += a1[hh];                                      \
    }                                                                                   \
    float i0 = 1.0f / s0, i1 = 1.0f / s1;                                               \
    _Pragma("unroll") for (int hh = 0; hh < 8; ++hh) {                                  \
      uint32_t pk = (uint32_t)f2bf(a0[hh] * i0) | ((uint32_t)f2bf(a1[hh] * i1) << 16);  \
      *(uint32_t*)&Ps[BUF][hh][n_][mp_] = pk;                                           \
    }                                                                                   \
  }
// PV: O[n][c] += P[n][m].V[c][m] ; A-frag = P rows n (b128), B = vf
#define PV(BUF)                                                                         \
  {                                                                                     \
    _Pragma("unroll") for (int fn = 0; fn < 2; ++fn) {                                  \
      short8 pa = *(const short8*)&Ps[BUF][h][fn * 16 + ln][8 * g];                     \
      _Pragma("unroll") for (int fc = 0; fc < 4; ++fc)                                  \
          oacc[fn][fc] = __builtin_amdgcn_mfma_f32_16x16x32_bf16(                       \
              pa, vf[fc], oacc[fn][fc], 0, 0, 0);                                       \
    }                                                                                   \
  }

  const float SC = 1.0f / 1024.0f;

  // prologue
  LOADQ(0); LOADV(0);
  QK(0); LOADQ(1);
  __syncthreads();
  QK(1); LOADQ(2); SM(0);
  __syncthreads();
  // main: phases p = 2..15
#pragma unroll
  for (int p = 2; p < 16; ++p) {
    if (p & 1) { PV(1); } else { PV(0); }      // step p-2, buf (p-2)&1 = p&1
    LOADV(p - 1);
    if (p & 1) { QK(1); } else { QK(0); }      // step p -> buf p&1
    LOADQ(p + 1 < 16 ? p + 1 : 15);
    if (p & 1) { SM(0); } else { SM(1); }      // step p-1, buf (p-1)&1
    __syncthreads();
  }
  // epilogue: phase 16: PV(14), SM(15); phase 17: PV(15)
  PV(0); SM(1);
  __syncthreads();
  LOADV(15);
  PV(1);

  // partial O (f32) for this m-chunk
#pragma unroll
  for (int fn = 0; fn < 2; ++fn)
#pragma unroll
    for (int fc = 0; fc < 4; ++fc)
#pragma unroll
      for (int r = 0; r < 4; ++r) {
        int np = n0 + fn * 16 + g * 4 + r;
        int c = h * 64 + fc * 16 + ln;
        part[(size_t)ch * 8192 * 512 + ((size_t)bb * 1024 + np) * 512 + c] = oacc[fn][fc][r];
      }
#undef LOADQ
#undef LOADV
#undef QK
#undef SM
#undef PV
}

// ---------------- K5b: reduce the two m-chunk partials -> att bf16 ----------------
__global__ __launch_bounds__(256) void k_reduce(const float* __restrict__ part,
                                                unsigned short* __restrict__ att) {
  size_t i = ((size_t)blockIdx.x * 256 + threadIdx.x) * 4;  // 4 f32 per thread
  float4 p0 = *(const float4*)&part[i];
  float4 p1 = *(const float4*)&part[(size_t)8192 * 512 + i];
  uint32_t lo = (uint32_t)f2bf(p0.x + p1.x) | ((uint32_t)f2bf(p0.y + p1.y) << 16);
  uint32_t hi = (uint32_t)f2bf(p0.z + p1.z) | ((uint32_t)f2bf(p0.w + p1.w) << 16);
  *(uint2*)&att[i] = make_uint2(lo, hi);
}

// ---------------- K6: LayerNorm over rows of [8192][256] ----------------
template <int MODE>
__global__ __launch_bounds__(256) void k_ln(const float* __restrict__ in,
                                            const float* __restrict__ g,
                                            const float* __restrict__ bta,
                                            float* __restrict__ out_f,
                                            unsigned short* __restrict__ out_b) {
  const int l = threadIdx.x & 63, w = threadIdx.x >> 6;
  const size_t row = (size_t)blockIdx.x * 4 + w;
  float4 xv = *(const float4*)(in + row * 256 + l * 4);
  float s = xv.x + xv.y + xv.z + xv.w;
  float q = xv.x * xv.x + xv.y * xv.y + xv.z * xv.z + xv.w * xv.w;
#pragma unroll
  for (int o = 1; o < 64; o <<= 1) {
    s += __shfl_xor(s, o, 64);
    q += __shfl_xor(q, o, 64);
  }
  float mu = s * (1.0f / 256.0f);
  float var = q * (1.0f / 256.0f) - mu * mu;
  float rstd = rsqrtf(var + 1e-5f);
  float4 gv = *(const float4*)(g + l * 4);
  float4 bv = *(const float4*)(bta + l * 4);
  float o0 = (xv.x - mu) * rstd * gv.x + bv.x;
  float o1 = (xv.y - mu) * rstd * gv.y + bv.y;
  float o2 = (xv.z - mu) * rstd * gv.z + bv.z;
  float o3 = (xv.w - mu) * rstd * gv.w + bv.w;
  *(float4*)(out_f + row * 256 + l * 4) = make_float4(o0, o1, o2, o3);
  if (MODE == 0) {
    uint32_t lo = (uint32_t)f2bf(o0) | ((uint32_t)f2bf(o1) << 16);
    uint32_t hi = (uint32_t)f2bf(o2) | ((uint32_t)f2bf(o3) << 16);
    *(uint2*)(out_b + row * 256 + l * 4) = make_uint2(lo, hi);
  }
}

// ---------------- K7: transpose [b*1024+n][256] -> d_out [b][256][1024] ----------------
__global__ __launch_bounds__(256) void k_transout(const float* __restrict__ in,
                                                  float* __restrict__ out) {
  __shared__ __align__(16) float tile[32][36];  // [c][n]
  const int b = blockIdx.z, c0 = blockIdx.x * 32, n0 = blockIdx.y * 32;
  const int t = threadIdx.x;
  {
    const int nl = t >> 3, cg = (t & 7) * 4;
    float4 v = *(const float4*)(in + ((size_t)b * 1024 + n0 + nl) * 256 + c0 + cg);
    tile[cg + 0][nl] = v.x;
    tile[cg + 1][nl] = v.y;
    tile[cg + 2][nl] = v.z;
    tile[cg + 3][nl] = v.w;
  }
  __syncthreads();
  {
    const int cl = t >> 3, ng = (t & 7) * 4;
    float4 o = make_float4(tile[cl][ng + 0], tile[cl][ng + 1], tile[cl][ng + 2], tile[cl][ng + 3]);
    *(float4*)(out + ((size_t)b * 256 + c0 + cl) * 1024 + n0 + ng) = o;
  }
}

// ---------------- host launcher ----------------
extern "C" void kernel_launch(void* const* d_in, const int* in_sizes, int n_in,
                              void* d_out, int out_size, void* d_ws, size_t ws_size,
                              hipStream_t stream) {
  const float* x     = (const float*)d_in[0];
  const float* Wk    = (const float*)d_in[1];
  const float* bk    = (const float*)d_in[2];
  const float* Wq    = (const float*)d_in[3];
  const float* bq    = (const float*)d_in[4];
  const float* Wv    = (const float*)d_in[5];
  const float* bv    = (const float*)d_in[6];
  const float* Wproj = (const float*)d_in[7];
  const float* bproj = (const float*)d_in[8];
  const float* ln_g  = (const float*)d_in[9];
  const float* ln_b  = (const float*)d_in[10];
  const float* W1    = (const float*)d_in[11];
  const float* b1    = (const float*)d_in[12];
  const float* W2    = (const float*)d_in[13];
  const float* b2    = (const float*)d_in[14];

  char* ws = (char*)d_ws;
  constexpr size_t OFF_XPTB  = 0;                                    // bf16 [8192][256]
  constexpr size_t OFF_XPTF  = OFF_XPTB  + (size_t)8192 * 256 * 2;   // f32  [8192][256]
  constexpr size_t OFF_WPACK = OFF_XPTF  + (size_t)8192 * 256 * 4;   // bf16 [1536][2304]
  constexpr size_t OFF_BIAS  = OFF_WPACK + (size_t)1536 * 2304 * 2;  // f32  [1536]
  constexpr size_t OFF_WPROJ = OFF_BIAS  + (size_t)1536 * 4;         // bf16 [256][512]
  constexpr size_t OFF_W1B   = OFF_WPROJ + (size_t)256 * 512 * 2;    // bf16 [256][256]
  constexpr size_t OFF_W2B   = OFF_W1B   + (size_t)256 * 256 * 2;    // bf16 [256][256]
  constexpr size_t OFF_PET   = OFF_W2B   + (size_t)256 * 256 * 2;    // f32  [256][32]
  constexpr size_t OFF_ZERO  = OFF_PET   + (size_t)256 * 32 * 4;     // f32  [64] zeros
  constexpr size_t OFF_KQT   = OFF_ZERO  + 256;                      // bf16 [8192][1024]
  constexpr size_t OFF_V     = OFF_KQT   + (size_t)8192 * 1024 * 2;  // bf16 [8][512][1024]
  constexpr size_t OFF_ATT   = OFF_V     + (size_t)8 * 512 * 1024 * 2; // bf16 [8192][512]
  constexpr size_t OFF_X     = OFF_ATT   + (size_t)8192 * 512 * 2;
  // region X: attn partials, then FFN-phase buffers
  constexpr size_t OFF_PART  = OFF_X;                                // f32  [2][8192][512]
  constexpr size_t OFF_Y1    = OFF_X;                                // f32 [8192][256]
  constexpr size_t OFF_ADDNF = OFF_Y1    + (size_t)8192 * 256 * 4;   // f32
  constexpr size_t OFF_ADDNB = OFF_ADDNF + (size_t)8192 * 256 * 4;   // bf16
  constexpr size_t OFF_H1    = OFF_ADDNB + (size_t)8192 * 256 * 2;   // bf16
  constexpr size_t OFF_H2    = OFF_H1    + (size_t)8192 * 256 * 2;   // f32

  (void)in_sizes; (void)n_in; (void)out_size; (void)ws_size;

  const char* zp = (const char*)(ws + OFF_ZERO);

  k_petab<<<1, 256, 0, stream>>>((float*)(ws + OFF_PET), (float*)(ws + OFF_ZERO));
  k_xpt<<<dim3(8, 32, 8), 256, 0, stream>>>(x, (const float*)(ws + OFF_PET),
                                            (unsigned short*)(ws + OFF_XPTB),
                                            (float*)(ws + OFF_XPTF));
  k_packw<<<(1536 * 2304 + 255) / 256, 256, 0, stream>>>(Wk, Wq, Wv,
                                                         (unsigned short*)(ws + OFF_WPACK));
  k_packmisc<<<512, 256, 0, stream>>>(bk, bq, bv, Wproj, W1, W2,
                                      (float*)(ws + OFF_BIAS),
                                      (unsigned short*)(ws + OFF_WPROJ),
                                      (unsigned short*)(ws + OFF_W1B),
                                      (unsigned short*)(ws + OFF_W2B));
  // conv K+Q: C[n][o] = im2col(xpt)[n][k] . Wkq[o][k]   (M=8192, N=1024, K=2304)
  k_gemm<0, true, false><<<dim3(64, 8, 1), 256, 0, stream>>>(
      (const unsigned short*)(ws + OFF_XPTB), (const unsigned short*)(ws + OFF_WPACK),
      ws + OFF_KQT, (const float*)(ws + OFF_BIAS), nullptr, zp,
      8192, 1024, 2304, 0, 0, 0);
  // conv V: C[o][m] = Wv[o][k] . im2col(xpt_b)[m][k]    (M=512, N=1024, K=2304, batched)
  k_gemm<1, false, true><<<dim3(4, 8, 8), 256, 0, stream>>>(
      (const unsigned short*)(ws + OFF_WPACK) + (size_t)1024 * 2304,
      (const unsigned short*)(ws + OFF_XPTB),
      ws + OFF_V, (const float*)(ws + OFF_BIAS) + 1024, nullptr, zp,
      512, 1024, 2304, 0, (size_t)1024 * 256, (size_t)512 * 1024);
  // fused attention (split-m over 2 chunks) + reduce
  k_attn<<<dim3(512), 512, 0, stream>>>((const unsigned short*)(ws + OFF_KQT),
                                        (const unsigned short*)(ws + OFF_V),
                                        (float*)(ws + OFF_PART));
  k_reduce<<<dim3(4096), 256, 0, stream>>>((const float*)(ws + OFF_PART),
                                           (unsigned short*)(ws + OFF_ATT));
  // attproj + bias + residual(x+pe): y1 f32      (M=8192, N=256, K=512)
  k_gemm<2, false, false><<<dim3(64, 2, 1), 256, 0, stream>>>(
      (const unsigned short*)(ws + OFF_ATT), (const unsigned short*)(ws + OFF_WPROJ),
      ws + OFF_Y1, bproj, (const float*)(ws + OFF_XPTF), zp,
      8192, 256, 512, 0, 0, 0);
  k_ln<0><<<2048, 256, 0, stream>>>((const float*)(ws + OFF_Y1), ln_g, ln_b,
                                    (float*)(ws + OFF_ADDNF), (unsigned short*)(ws + OFF_ADDNB));
  // FFN1 + LeakyReLU
  k_gemm<3, false, false><<<dim3(64, 2, 1), 256, 0, stream>>>(
      (const unsigned short*)(ws + OFF_ADDNB), (const unsigned short*)(ws + OFF_W1B),
      ws + OFF_H1, b1, nullptr, zp, 8192, 256, 256, 0, 0, 0);
  // FFN2 + bias + residual(addnormed)
  k_gemm<2, false, false><<<dim3(64, 2, 1), 256, 0, stream>>>(
      (const unsigned short*)(ws + OFF_H1), (const unsigned short*)(ws + OFF_W2B),
      ws + OFF_H2, b2, (const float*)(ws + OFF_ADDNF), zp,
      8192, 256, 256, 0, 0, 0);
  k_ln<1><<<2048, 256, 0, stream>>>((const float*)(ws + OFF_H2), ln_g, ln_b,
                                    (float*)(ws + OFF_Y1), nullptr);
  k_transout<<<dim3(8, 32, 8), 256, 0, stream>>>((const float*)(ws + OFF_Y1), (float*)d_out);
}

// Round 4
// 243.783 us; speedup vs baseline: 1.2144x; 1.0640x over previous
//
#include <hip/hip_runtime.h>
#include <stdint.h>

typedef __attribute__((ext_vector_type(8))) short short8;
typedef __attribute__((ext_vector_type(4))) short s16x4;
typedef __attribute__((ext_vector_type(4))) float f32x4;

#define DEVI __device__ __forceinline__

#if __has_builtin(__builtin_amdgcn_mfma_f32_16x16x16_bf16)
#define MFMA16(a, b, c) __builtin_amdgcn_mfma_f32_16x16x16_bf16(a, b, c, 0, 0, 0)
#else
#define MFMA16(a, b, c) __builtin_amdgcn_mfma_f32_16x16x16bf16_1k(a, b, c, 0, 0, 0)
#endif

DEVI unsigned short f2bf(float f) {
  union { float f; uint32_t u; } v; v.f = f;
  return (unsigned short)((v.u + 0x7fffu + ((v.u >> 16) & 1u)) >> 16);
}

DEVI float bf2f(uint32_t hi16) {  // bits already in [31:16]
  union { uint32_t u; float f; } v; v.u = hi16;
  return v.f;
}

DEVI uint32_t pkbf(float a, float b) {  // fast RTN pack (positive values)
  union { float f; uint32_t u; } x, y; x.f = a; y.f = b;
  return ((x.u + 0x8000u) >> 16) | (((y.u + 0x8000u) >> 16) << 16);
}

DEVI void gload_lds16(const void* g, void* l) {
  __builtin_amdgcn_global_load_lds(
      (const __attribute__((address_space(1))) uint32_t*)g,
      (__attribute__((address_space(3))) uint32_t*)l, 16, 0, 0);
}

// ---------------- K0: positional encoding table T[256][32] + zero page ----------------
__global__ void k_petab(float* __restrict__ T, float* __restrict__ zp) {
  int c = threadIdx.x;  // 256 threads
  if (c < 64) zp[c] = 0.0f;
  int idx = ((c >= 128) ? c - 128 : c) >> 1;
  float freq = expf(-(float)idx * (logf(10000.0f) / 64.0f));
  for (int p = 0; p < 32; ++p) {
    float ang = (float)p * freq;
    T[c * 32 + p] = (c & 1) ? cosf(ang) : sinf(ang);
  }
}

// ---------------- K1: xpT = (x + pe) transposed to [b*1024+n][256], f32 + bf16 ----------------
__global__ __launch_bounds__(256) void k_xpt(const float* __restrict__ x,
                                             const float* __restrict__ T,
                                             unsigned short* __restrict__ xpt_bf,
                                             float* __restrict__ xpt_f) {
  __shared__ __align__(16) float tile[32][36];  // [n][c]
  const int b = blockIdx.z, c0 = blockIdx.x * 32, n0 = blockIdx.y * 32;
  const int t = threadIdx.x;
  {
    const int cl = t >> 3, ng = (t & 7) * 4;
    const int c = c0 + cl;
    float4 v = *(const float4*)(x + ((size_t)b * 256 + c) * 1024 + n0 + ng);
    float p0, p1, p2, p3;
    if (c < 128) {
      p0 = T[c * 32 + ng + 0]; p1 = T[c * 32 + ng + 1];
      p2 = T[c * 32 + ng + 2]; p3 = T[c * 32 + ng + 3];
    } else {
      p0 = p1 = p2 = p3 = T[c * 32 + (n0 >> 5)];
    }
    tile[ng + 0][cl] = v.x + p0;
    tile[ng + 1][cl] = v.y + p1;
    tile[ng + 2][cl] = v.z + p2;
    tile[ng + 3][cl] = v.w + p3;
  }
  __syncthreads();
  {
    const int nl = t >> 3, cg = (t & 7) * 4;
    float o0 = tile[nl][cg + 0], o1 = tile[nl][cg + 1];
    float o2 = tile[nl][cg + 2], o3 = tile[nl][cg + 3];
    size_t row = (size_t)b * 1024 + n0 + nl;
    *(float4*)(xpt_f + row * 256 + c0 + cg) = make_float4(o0, o1, o2, o3);
    uint32_t lo = (uint32_t)f2bf(o0) | ((uint32_t)f2bf(o1) << 16);
    uint32_t hi = (uint32_t)f2bf(o2) | ((uint32_t)f2bf(o3) << 16);
    *(uint2*)(xpt_bf + row * 256 + c0 + cg) = make_uint2(lo, hi);
  }
}

// ---------------- K2: pack conv weights -> Wpack[1536][2304] bf16 ----------------
__global__ void k_packw(const float* __restrict__ Wk, const float* __restrict__ Wq,
                        const float* __restrict__ Wv, unsigned short* __restrict__ Wpack) {
  int i = blockIdx.x * 256 + threadIdx.x;
  if (i >= 1536 * 2304) return;
  int o = i / 2304, kn = i % 2304;
  int ci = kn & 255, khw = kn >> 8;
  const float* src = (o < 512) ? Wk : ((o < 1024) ? Wq : Wv);
  int oo = o & 511;
  Wpack[i] = f2bf(src[((size_t)oo * 256 + ci) * 9 + khw]);
}

// ---------------- K3: misc packs ----------------
__global__ void k_packmisc(const float* __restrict__ bk, const float* __restrict__ bq,
                           const float* __restrict__ bv, const float* __restrict__ Wproj,
                           const float* __restrict__ W1, const float* __restrict__ W2,
                           float* __restrict__ bias_kqv, unsigned short* __restrict__ WprojP,
                           unsigned short* __restrict__ W1b, unsigned short* __restrict__ W2b) {
  int i = blockIdx.x * 256 + threadIdx.x;
  if (i < 1536)
    bias_kqv[i] = (i < 512) ? bk[i] : ((i < 1024) ? bq[i - 512] : bv[i - 1024]);
  if (i < 131072) {
    int j = i >> 9, f = i & 511;
    int h = f >> 6, c = f & 63;
    WprojP[i] = f2bf(Wproj[(size_t)j * 512 + c * 8 + h]);
  }
  if (i < 65536) {
    W1b[i] = f2bf(W1[i]);
    W2b[i] = f2bf(W2[i]);
  }
}

// ---------------- implicit-im2col source address ----------------
DEVI const char* imp_src(const unsigned short* base, int r_loc, int dy, int dx, int ci,
                         const char* zp) {
  int nl = r_loc & 1023, pg = r_loc >> 10;
  int y = (nl >> 5) + dy, xx = (nl & 31) + dx;
  const char* s = (const char*)base + ((((size_t)pg << 10) + y * 32 + xx) * 256 + ci) * 2;
  return (((unsigned)y < 32u) && ((unsigned)xx < 32u)) ? s : zp;
}

// ---------------- merged conv GEMM: C[8192][1536] = im2col(xpt) . Wpack^T ----------------
// n0 < 1024: kq_t[m][o] bf16 (+bias).  n0 >= 1024: v[b][o-1024][m] bf16 (+bias), transposed store.
__global__ __launch_bounds__(256) void k_gemm_conv(const unsigned short* __restrict__ xpt,
                                                   const unsigned short* __restrict__ Wp,
                                                   unsigned short* __restrict__ kq_t,
                                                   unsigned short* __restrict__ vout,
                                                   const float* __restrict__ bias,
                                                   const char* __restrict__ zp) {
  __shared__ __align__(16) unsigned short As[128 * 64];
  __shared__ __align__(16) unsigned short Bs[128 * 64];
  const int tid = threadIdx.x, l = tid & 63, w = tid >> 6;
  const int wm = w >> 1, wn = w & 1, g = l >> 4, ln = l & 15;
  const int m0 = blockIdx.x * 128, n0 = blockIdx.y * 128;
  const int swz = (l & 7) ^ (l >> 3);
  f32x4 acc[4][4] = {};

  for (int kt = 0; kt < 2304; kt += 64) {
    int khw = kt >> 8;
    int dy = khw / 3 - 1, dx = khw - (khw / 3) * 3 - 1;
    int ci = (kt & 255) + swz * 8;
#pragma unroll
    for (int j = 0; j < 4; ++j) {
      int seg = w * 4 + j;
      int r8 = seg * 8 + (l >> 3);
      gload_lds16(imp_src(xpt, m0 + r8, dy, dx, ci, zp), (char*)As + seg * 1024);
      gload_lds16((const char*)Wp + ((size_t)(n0 + r8) * 2304 + kt + swz * 8) * 2,
                  (char*)Bs + seg * 1024);
    }
    __syncthreads();
#pragma unroll
    for (int kk = 0; kk < 2; ++kk) {
      short8 af[4], bfr[4];
#pragma unroll
      for (int fm = 0; fm < 4; ++fm)
        af[fm] = *(const short8*)((const char*)As + (wm * 64 + fm * 16 + ln) * 128 +
                                  (((kk * 4 + g) ^ (ln & 7)) * 16));
#pragma unroll
      for (int fn = 0; fn < 4; ++fn)
        bfr[fn] = *(const short8*)((const char*)Bs + (wn * 64 + fn * 16 + ln) * 128 +
                                   (((kk * 4 + g) ^ (ln & 7)) * 16));
#pragma unroll
      for (int fm = 0; fm < 4; ++fm)
#pragma unroll
        for (int fn = 0; fn < 4; ++fn)
          acc[fm][fn] = __builtin_amdgcn_mfma_f32_16x16x32_bf16(af[fm], bfr[fn], acc[fm][fn], 0, 0, 0);
    }
    __syncthreads();
  }

  if (n0 < 1024) {
#pragma unroll
    for (int fm = 0; fm < 4; ++fm)
#pragma unroll
      for (int fn = 0; fn < 4; ++fn)
#pragma unroll
        for (int r = 0; r < 4; ++r) {
          int row = m0 + wm * 64 + fm * 16 + g * 4 + r;
          int col = n0 + wn * 64 + fn * 16 + ln;
          kq_t[(size_t)row * 1024 + col] = f2bf(acc[fm][fn][r] + bias[col]);
        }
  } else {
    const int b = m0 >> 10, ml0 = m0 & 1023;
#pragma unroll
    for (int fm = 0; fm < 4; ++fm)
#pragma unroll
      for (int fn = 0; fn < 4; ++fn) {
        int colg = n0 + wn * 64 + fn * 16 + ln;
        float bb = bias[colg];
        int c = colg - 1024;
#pragma unroll
        for (int r2 = 0; r2 < 2; ++r2) {
          int ml = ml0 + wm * 64 + fm * 16 + g * 4 + r2 * 2;
          uint32_t u = (uint32_t)f2bf(acc[fm][fn][2 * r2] + bb) |
                       ((uint32_t)f2bf(acc[fm][fn][2 * r2 + 1] + bb) << 16);
          *(uint32_t*)&vout[((size_t)b * 512 + c) * 1024 + ml] = u;
        }
      }
  }
}

// ---------------- GEMM BN=64: C[M][N] = A[M][K].B[N][K]^T, tile 128x64, 4 waves ----------------
// EPI 2: f32 out, + bias[col] + resid;  EPI 3: bf16 out, + bias[col], LeakyReLU(0.1)
template <int EPI>
__global__ __launch_bounds__(256) void k_gemm64(const unsigned short* __restrict__ A,
                                                const unsigned short* __restrict__ B,
                                                void* __restrict__ Cout,
                                                const float* __restrict__ bias,
                                                const float* __restrict__ resid,
                                                int N, int K) {
  __shared__ __align__(16) unsigned short As[128 * 64];
  __shared__ __align__(16) unsigned short Bs[64 * 64];
  const int tid = threadIdx.x, l = tid & 63, w = tid >> 6;
  const int g = l >> 4, ln = l & 15;
  const int m0 = blockIdx.x * 128, n0 = blockIdx.y * 64;
  const int swz = (l & 7) ^ (l >> 3);
  f32x4 acc[2][4] = {};

  for (int kt = 0; kt < K; kt += 64) {
#pragma unroll
    for (int j = 0; j < 4; ++j) {
      int seg = w * 4 + j;
      int r8 = seg * 8 + (l >> 3);
      gload_lds16((const char*)A + ((size_t)(m0 + r8) * K + kt + swz * 8) * 2,
                  (char*)As + seg * 1024);
    }
#pragma unroll
    for (int j = 0; j < 2; ++j) {
      int seg = w * 2 + j;
      int r8 = seg * 8 + (l >> 3);
      gload_lds16((const char*)B + ((size_t)(n0 + r8) * K + kt + swz * 8) * 2,
                  (char*)Bs + seg * 1024);
    }
    __syncthreads();
#pragma unroll
    for (int kk = 0; kk < 2; ++kk) {
      short8 af[2], bfr[4];
#pragma unroll
      for (int fm = 0; fm < 2; ++fm)
        af[fm] = *(const short8*)((const char*)As + (w * 32 + fm * 16 + ln) * 128 +
                                  (((kk * 4 + g) ^ (ln & 7)) * 16));
#pragma unroll
      for (int fn = 0; fn < 4; ++fn)
        bfr[fn] = *(const short8*)((const char*)Bs + (fn * 16 + ln) * 128 +
                                   (((kk * 4 + g) ^ (ln & 7)) * 16));
#pragma unroll
      for (int fm = 0; fm < 2; ++fm)
#pragma unroll
        for (int fn = 0; fn < 4; ++fn)
          acc[fm][fn] = __builtin_amdgcn_mfma_f32_16x16x32_bf16(af[fm], bfr[fn], acc[fm][fn], 0, 0, 0);
    }
    __syncthreads();
  }

#pragma unroll
  for (int fm = 0; fm < 2; ++fm)
#pragma unroll
    for (int fn = 0; fn < 4; ++fn)
#pragma unroll
      for (int r = 0; r < 4; ++r) {
        int row = m0 + w * 32 + fm * 16 + g * 4 + r;
        int col = n0 + fn * 16 + ln;
        float v = acc[fm][fn][r] + bias[col];
        size_t cidx = (size_t)row * N + col;
        if (EPI == 2) {
          ((float*)Cout)[cidx] = v + resid[cidx];
        } else {
          v = (v > 0.f) ? v : 0.1f * v;
          ((unsigned short*)Cout)[cidx] = f2bf(v);
        }
      }
}

// ---------------- K5: fused attention v4 — all-heads-per-wave, in-register softmax ----------------
// Head-axis softmax: the 8 head scores for a (m,n) position live in ONE lane after
// 8 QK MFMAs -> softmax is pure in-register (no max needed, |S|<<1). The k=16 PV MFMA
// B-fragment layout (col=ln, k=4g+j) EXACTLY matches the QK C-layout (m=4g+r, n=ln),
// so P feeds PV directly from registers. No S/P LDS, no cross-wave traffic.
// Block = 4 waves (4 n-tiles of 16) sharing double-buffered LDS Q/V tiles; 1 barrier/step.
// 512 blocks: id = b(&7, XCD-local) + 8*ngroup(16) + 128*chunk(4); 16 steps x 16m.
__global__ __launch_bounds__(256, 2) void k_attn(const unsigned short* __restrict__ kq_t,
                                                 const unsigned short* __restrict__ v,
                                                 unsigned short* __restrict__ part) {
  __shared__ __align__(16) unsigned short Qs[2][16][512];  // [buf][m][c'] c'-chunks XOR-swizzled by m&7
  __shared__ __align__(16) unsigned short Vs[2][512][24];  // [buf][c][m(16)+pad8] rows 48B (16B-aligned)
  const int tid = threadIdx.x, l = tid & 63, w = tid >> 6;
  const int g = l >> 4, ln = l & 15;
  const int id = blockIdx.x;
  const int b = id & 7, ng = (id >> 3) & 15, ch = id >> 7;
  const int n0 = ng * 64 + w * 16;
  const int m_base = ch * 256;
  const size_t kqBase = (size_t)b << 20;
  const size_t vBase = (size_t)b * 512 * 1024;
  const float SC = 1.0f / 1024.0f;

  // K fragments (B operand), resident: ak[h][kk] covers this wave's 16 n, all heads
  short8 ak[8][2];
#pragma unroll
  for (int h = 0; h < 8; ++h)
#pragma unroll
    for (int kk = 0; kk < 2; ++kk)
      ak[h][kk] = *(const short8*)&kq_t[kqBase + (size_t)(n0 + ln) * 1024 + h * 64 + kk * 32 + g * 8];

  f32x4 acc[8][4] = {};  // O[c][n]: c = h*64+cf*16+4g+r, n = n0+ln

  auto STAGE = [&](int buf, int m0s) {
#pragma unroll
    for (int i = 0; i < 4; ++i) {   // Q: 16 rows x 512 c (swizzled source)
      int mq = i * 4 + w;
      gload_lds16(kq_t + kqBase + (size_t)(m0s + mq) * 1024 + 512 + ((l ^ (mq & 7)) * 8),
                  (char*)Qs + buf * 16384 + i * 4096 + w * 1024);
    }
#pragma unroll
    for (int i = 0; i < 6; ++i) {   // V: 512 rows x 16 m into 48B rows (pad chunk harmless dup)
      int q16 = i * 256 + w * 64 + l;
      int c = (q16 * 43691) >> 17;  // q16 / 3
      int m8 = (q16 - c * 3) & 1;
      gload_lds16(v + vBase + (size_t)c * 1024 + m0s + m8 * 8,
                  (char*)Vs + buf * 24576 + i * 4096 + w * 1024);
    }
  };

  STAGE(0, m_base);
  __syncthreads();

  for (int s = 0; s < 16; ++s) {
    const int buf = s & 1;
    if (s < 15) STAGE(buf ^ 1, m_base + (s + 1) * 16);

    // --- QK^T: S[m][n] per head, in registers ---
    f32x4 sv[8];
#pragma unroll
    for (int h = 0; h < 8; ++h) sv[h] = f32x4{0.f, 0.f, 0.f, 0.f};
#pragma unroll
    for (int kk = 0; kk < 2; ++kk)
#pragma unroll
      for (int h = 0; h < 8; ++h) {
        short8 qa = *(const short8*)((const char*)Qs + buf * 16384 + ln * 1024 +
                                     (((h * 8 + kk * 4 + g) ^ (ln & 7)) * 16));
        sv[h] = __builtin_amdgcn_mfma_f32_16x16x32_bf16(qa, ak[h][kk], sv[h], 0, 0, 0);
      }

    // --- softmax over heads, fully in-register (no max: |S/1024| << 1) ---
    float s0 = 0.f, s1 = 0.f, s2 = 0.f, s3 = 0.f;
#pragma unroll
    for (int h = 0; h < 8; ++h) {
      sv[h][0] = __expf(sv[h][0] * SC); s0 += sv[h][0];
      sv[h][1] = __expf(sv[h][1] * SC); s1 += sv[h][1];
      sv[h][2] = __expf(sv[h][2] * SC); s2 += sv[h][2];
      sv[h][3] = __expf(sv[h][3] * SC); s3 += sv[h][3];
    }
    float i0 = 1.0f / s0, i1 = 1.0f / s1, i2 = 1.0f / s2, i3 = 1.0f / s3;

    // --- PV: P (registers) as B-operand of k=16 MFMA ---
#pragma unroll
    for (int h = 0; h < 8; ++h) {
      union { uint32_t u[2]; s16x4 v4; } pc;
      pc.u[0] = pkbf(sv[h][0] * i0, sv[h][1] * i1);
      pc.u[1] = pkbf(sv[h][2] * i2, sv[h][3] * i3);
#pragma unroll
      for (int cf = 0; cf < 4; ++cf) {
        s16x4 vf = *(const s16x4*)((const char*)Vs + buf * 24576 +
                                   (h * 64 + cf * 16 + ln) * 48 + g * 8);
        acc[h][cf] = MFMA16(vf, pc.v4, acc[h][cf]);
      }
    }
    __syncthreads();
  }

  // partial O (bf16) for this m-chunk: rows n, cols c (u32-packed pairs along c)
  const size_t outBase = (size_t)ch * 8192 * 512 + ((size_t)b * 1024 + n0 + ln) * 512;
#pragma unroll
  for (int h = 0; h < 8; ++h)
#pragma unroll
    for (int cf = 0; cf < 4; ++cf)
#pragma unroll
      for (int r2 = 0; r2 < 2; ++r2) {
        int c = h * 64 + cf * 16 + g * 4 + r2 * 2;
        uint32_t u = (uint32_t)f2bf(acc[h][cf][2 * r2]) |
                     ((uint32_t)f2bf(acc[h][cf][2 * r2 + 1]) << 16);
        *(uint32_t*)&part[outBase + c] = u;
      }
}

// ---------------- K5b: reduce the four m-chunk partials (bf16) -> att bf16 ----------------
__global__ __launch_bounds__(256) void k_reduce4(const unsigned short* __restrict__ part,
                                                 unsigned short* __restrict__ att) {
  size_t i8 = ((size_t)blockIdx.x * 256 + threadIdx.x) * 8;
  float o[8] = {0.f, 0.f, 0.f, 0.f, 0.f, 0.f, 0.f, 0.f};
#pragma unroll
  for (int p = 0; p < 4; ++p) {
    uint4 u = *(const uint4*)&part[(size_t)p * 8192 * 512 + i8];
    uint32_t a[4] = {u.x, u.y, u.z, u.w};
#pragma unroll
    for (int j = 0; j < 4; ++j) {
      o[2 * j] += bf2f(a[j] << 16);
      o[2 * j + 1] += bf2f(a[j] & 0xffff0000u);
    }
  }
  uint32_t r0 = (uint32_t)f2bf(o[0]) | ((uint32_t)f2bf(o[1]) << 16);
  uint32_t r1 = (uint32_t)f2bf(o[2]) | ((uint32_t)f2bf(o[3]) << 16);
  uint32_t r2 = (uint32_t)f2bf(o[4]) | ((uint32_t)f2bf(o[5]) << 16);
  uint32_t r3 = (uint32_t)f2bf(o[6]) | ((uint32_t)f2bf(o[7]) << 16);
  *(uint4*)&att[i8] = make_uint4(r0, r1, r2, r3);
}

// ---------------- K6: LayerNorm over rows of [8192][256] ----------------
template <int MODE>
__global__ __launch_bounds__(256) void k_ln(const float* __restrict__ in,
                                            const float* __restrict__ g,
                                            const float* __restrict__ bta,
                                            float* __restrict__ out_f,
                                            unsigned short* __restrict__ out_b) {
  const int l = threadIdx.x & 63, w = threadIdx.x >> 6;
  const size_t row = (size_t)blockIdx.x * 4 + w;
  float4 xv = *(const float4*)(in + row * 256 + l * 4);
  float s = xv.x + xv.y + xv.z + xv.w;
  float q = xv.x * xv.x + xv.y * xv.y + xv.z * xv.z + xv.w * xv.w;
#pragma unroll
  for (int o = 1; o < 64; o <<= 1) {
    s += __shfl_xor(s, o, 64);
    q += __shfl_xor(q, o, 64);
  }
  float mu = s * (1.0f / 256.0f);
  float var = q * (1.0f / 256.0f) - mu * mu;
  float rstd = rsqrtf(var + 1e-5f);
  float4 gv = *(const float4*)(g + l * 4);
  float4 bv = *(const float4*)(bta + l * 4);
  float o0 = (xv.x - mu) * rstd * gv.x + bv.x;
  float o1 = (xv.y - mu) * rstd * gv.y + bv.y;
  float o2 = (xv.z - mu) * rstd * gv.z + bv.z;
  float o3 = (xv.w - mu) * rstd * gv.w + bv.w;
  *(float4*)(out_f + row * 256 + l * 4) = make_float4(o0, o1, o2, o3);
  if (MODE == 0) {
    uint32_t lo = (uint32_t)f2bf(o0) | ((uint32_t)f2bf(o1) << 16);
    uint32_t hi = (uint32_t)f2bf(o2) | ((uint32_t)f2bf(o3) << 16);
    *(uint2*)(out_b + row * 256 + l * 4) = make_uint2(lo, hi);
  }
}

// ---------------- K7: transpose [b*1024+n][256] -> d_out [b][256][1024] ----------------
__global__ __launch_bounds__(256) void k_transout(const float* __restrict__ in,
                                                  float* __restrict__ out) {
  __shared__ __align__(16) float tile[32][36];
  const int b = blockIdx.z, c0 = blockIdx.x * 32, n0 = blockIdx.y * 32;
  const int t = threadIdx.x;
  {
    const int nl = t >> 3, cg = (t & 7) * 4;
    float4 v = *(const float4*)(in + ((size_t)b * 1024 + n0 + nl) * 256 + c0 + cg);
    tile[cg + 0][nl] = v.x;
    tile[cg + 1][nl] = v.y;
    tile[cg + 2][nl] = v.z;
    tile[cg + 3][nl] = v.w;
  }
  __syncthreads();
  {
    const int cl = t >> 3, ng = (t & 7) * 4;
    float4 o = make_float4(tile[cl][ng + 0], tile[cl][ng + 1], tile[cl][ng + 2], tile[cl][ng + 3]);
    *(float4*)(out + ((size_t)b * 256 + c0 + cl) * 1024 + n0 + ng) = o;
  }
}

// ---------------- host launcher ----------------
extern "C" void kernel_launch(void* const* d_in, const int* in_sizes, int n_in,
                              void* d_out, int out_size, void* d_ws, size_t ws_size,
                              hipStream_t stream) {
  const float* x     = (const float*)d_in[0];
  const float* Wk    = (const float*)d_in[1];
  const float* bk    = (const float*)d_in[2];
  const float* Wq    = (const float*)d_in[3];
  const float* bq    = (const float*)d_in[4];
  const float* Wv    = (const float*)d_in[5];
  const float* bv    = (const float*)d_in[6];
  const float* Wproj = (const float*)d_in[7];
  const float* bproj = (const float*)d_in[8];
  const float* ln_g  = (const float*)d_in[9];
  const float* ln_b  = (const float*)d_in[10];
  const float* W1    = (const float*)d_in[11];
  const float* b1    = (const float*)d_in[12];
  const float* W2    = (const float*)d_in[13];
  const float* b2    = (const float*)d_in[14];

  char* ws = (char*)d_ws;
  constexpr size_t OFF_XPTB  = 0;                                    // bf16 [8192][256]
  constexpr size_t OFF_XPTF  = OFF_XPTB  + (size_t)8192 * 256 * 2;   // f32  [8192][256]
  constexpr size_t OFF_WPACK = OFF_XPTF  + (size_t)8192 * 256 * 4;   // bf16 [1536][2304]
  constexpr size_t OFF_BIAS  = OFF_WPACK + (size_t)1536 * 2304 * 2;  // f32  [1536]
  constexpr size_t OFF_WPROJ = OFF_BIAS  + (size_t)1536 * 4;         // bf16 [256][512]
  constexpr size_t OFF_W1B   = OFF_WPROJ + (size_t)256 * 512 * 2;    // bf16 [256][256]
  constexpr size_t OFF_W2B   = OFF_W1B   + (size_t)256 * 256 * 2;    // bf16 [256][256]
  constexpr size_t OFF_PET   = OFF_W2B   + (size_t)256 * 256 * 2;    // f32  [256][32]
  constexpr size_t OFF_ZERO  = OFF_PET   + (size_t)256 * 32 * 4;     // f32  [64] zeros
  constexpr size_t OFF_KQT   = OFF_ZERO  + 256;                      // bf16 [8192][1024]
  constexpr size_t OFF_V     = OFF_KQT   + (size_t)8192 * 1024 * 2;  // bf16 [8][512][1024]
  constexpr size_t OFF_ATT   = OFF_V     + (size_t)8 * 512 * 1024 * 2; // bf16 [8192][512]
  constexpr size_t OFF_X     = OFF_ATT   + (size_t)8192 * 512 * 2;
  // region X: attn partials (4 x bf16 [8192][512] = 33.5MB), then FFN-phase buffers
  constexpr size_t OFF_PART  = OFF_X;
  constexpr size_t OFF_Y1    = OFF_X;                                // f32 [8192][256]
  constexpr size_t OFF_ADDNF = OFF_Y1    + (size_t)8192 * 256 * 4;   // f32
  constexpr size_t OFF_ADDNB = OFF_ADDNF + (size_t)8192 * 256 * 4;   // bf16
  constexpr size_t OFF_H1    = OFF_ADDNB + (size_t)8192 * 256 * 2;   // bf16
  constexpr size_t OFF_H2    = OFF_H1    + (size_t)8192 * 256 * 2;   // f32

  (void)in_sizes; (void)n_in; (void)out_size; (void)ws_size;

  const char* zp = (const char*)(ws + OFF_ZERO);

  k_petab<<<1, 256, 0, stream>>>((float*)(ws + OFF_PET), (float*)(ws + OFF_ZERO));
  k_xpt<<<dim3(8, 32, 8), 256, 0, stream>>>(x, (const float*)(ws + OFF_PET),
                                            (unsigned short*)(ws + OFF_XPTB),
                                            (float*)(ws + OFF_XPTF));
  k_packw<<<(1536 * 2304 + 255) / 256, 256, 0, stream>>>(Wk, Wq, Wv,
                                                         (unsigned short*)(ws + OFF_WPACK));
  k_packmisc<<<512, 256, 0, stream>>>(bk, bq, bv, Wproj, W1, W2,
                                      (float*)(ws + OFF_BIAS),
                                      (unsigned short*)(ws + OFF_WPROJ),
                                      (unsigned short*)(ws + OFF_W1B),
                                      (unsigned short*)(ws + OFF_W2B));
  // merged conv K+Q+V: C[8192][1536] (M=8192, N=1536, K=2304)
  k_gemm_conv<<<dim3(64, 12), 256, 0, stream>>>(
      (const unsigned short*)(ws + OFF_XPTB), (const unsigned short*)(ws + OFF_WPACK),
      (unsigned short*)(ws + OFF_KQT), (unsigned short*)(ws + OFF_V),
      (const float*)(ws + OFF_BIAS), zp);
  // fused attention (split-m over 4 chunks) + reduce
  k_attn<<<dim3(512), 256, 0, stream>>>((const unsigned short*)(ws + OFF_KQT),
                                        (const unsigned short*)(ws + OFF_V),
                                        (unsigned short*)(ws + OFF_PART));
  k_reduce4<<<dim3(2048), 256, 0, stream>>>((const unsigned short*)(ws + OFF_PART),
                                            (unsigned short*)(ws + OFF_ATT));
  // attproj + bias + residual(x+pe): y1 f32   (M=8192, N=256, K=512)
  k_gemm64<2><<<dim3(64, 4), 256, 0, stream>>>(
      (const unsigned short*)(ws + OFF_ATT), (const unsigned short*)(ws + OFF_WPROJ),
      ws + OFF_Y1, bproj, (const float*)(ws + OFF_XPTF), 256, 512);
  k_ln<0><<<2048, 256, 0, stream>>>((const float*)(ws + OFF_Y1), ln_g, ln_b,
                                    (float*)(ws + OFF_ADDNF), (unsigned short*)(ws + OFF_ADDNB));
  // FFN1 + LeakyReLU
  k_gemm64<3><<<dim3(64, 4), 256, 0, stream>>>(
      (const unsigned short*)(ws + OFF_ADDNB), (const unsigned short*)(ws + OFF_W1B),
      ws + OFF_H1, b1, nullptr, 256, 256);
  // FFN2 + bias + residual(addnormed)
  k_gemm64<2><<<dim3(64, 4), 256, 0, stream>>>(
      (const unsigned short*)(ws + OFF_H1), (const unsigned short*)(ws + OFF_W2B),
      ws + OFF_H2, b2, (const float*)(ws + OFF_ADDNF), 256, 256);
  k_ln<1><<<2048, 256, 0, stream>>>((const float*)(ws + OFF_H2), ln_g, ln_b,
                                    (float*)(ws + OFF_Y1), nullptr);
  k_transout<<<dim3(8, 32, 8), 256, 0, stream>>>((const float*)(ws + OFF_Y1), (float*)d_out);
}